// Round 2
// baseline (479.240 us; speedup 1.0000x reference)
//
#include <hip/hip_runtime.h>

#define T_    1024
#define H_    1024
#define IDIM  1024
#define E_    16
#define TOPK  4
#define ALPHA 1.702f
#define LIMIT 7.0f

typedef __bf16 bf16;
typedef __bf16 bf16x4 __attribute__((ext_vector_type(4)));
typedef __bf16 bf16x8 __attribute__((ext_vector_type(8)));
typedef float  f32x4  __attribute__((ext_vector_type(4)));

// ---------------------------------------------------------------------------
// Kernel 1: RMSNorm + router logits + softmax/top-4 + routing lists.
// ---------------------------------------------------------------------------
__global__ __launch_bounds__(256) void k_rms_router(
    const float* __restrict__ x, const float* __restrict__ nw,
    const float* __restrict__ rw, const float* __restrict__ rb,
    const float* __restrict__ mw, const int* __restrict__ lidx,
    bf16* __restrict__ tB, float* __restrict__ out,
    int* __restrict__ cnt, int* __restrict__ tok_list,
    float* __restrict__ wgt_list)
{
    const int t = blockIdx.x, tid = threadIdx.x;
    const int lane = tid & 63, wave = tid >> 6;
    __shared__ float tbuf[H_];
    __shared__ float red[4];
    __shared__ float logits[E_];

    float4 xv = ((const float4*)(x + (size_t)t * H_))[tid];
    float4 wv = ((const float4*)nw)[tid];
    float ssq = xv.x*xv.x + xv.y*xv.y + xv.z*xv.z + xv.w*xv.w;
    #pragma unroll
    for (int off = 32; off; off >>= 1) ssq += __shfl_xor(ssq, off);
    if (lane == 0) red[wave] = ssq;
    __syncthreads();
    const float rms = rsqrtf((red[0] + red[1] + red[2] + red[3]) * (1.0f / H_) + 1e-5f);

    float4 tv;
    tv.x = xv.x * rms * wv.x;
    tv.y = xv.y * rms * wv.y;
    tv.z = xv.z * rms * wv.z;
    tv.w = xv.w * rms * wv.w;

    ((float4*)(out + (size_t)t * H_))[tid] = xv;      // residual init
    ((float4*)tbuf)[tid] = tv;
    bf16x4 tb = { (bf16)tv.x, (bf16)tv.y, (bf16)tv.z, (bf16)tv.w };
    *(bf16x4*)(tB + (size_t)t * H_ + tid * 4) = tb;
    __syncthreads();

    #pragma unroll
    for (int ei = 0; ei < 4; ++ei) {
        const int e = wave * 4 + ei;
        const float* wr = rw + (size_t)e * H_;
        float s = 0.f;
        #pragma unroll
        for (int j = 0; j < 16; ++j) {
            const int c = lane + j * 64;
            s += tbuf[c] * wr[c];
        }
        #pragma unroll
        for (int off = 32; off; off >>= 1) s += __shfl_xor(s, off);
        if (lane == 0) logits[e] = s + rb[e];
    }
    __syncthreads();

    if (tid == 0) {
        float g[E_];
        #pragma unroll
        for (int e = 0; e < E_; ++e) g[e] = logits[e];

        const int li = lidx[0];
        float ma = 0.f, lw[E_];
        #pragma unroll
        for (int e = 0; e < E_; ++e) { lw[e] = mw[li * E_ + e]; ma = fmaxf(ma, fabsf(lw[e])); }
        if (ma > 0.f) {
            float mx = -1e30f;
            for (int e = 0; e < E_; ++e) mx = fmaxf(mx, g[e]);
            float se = 0.f;
            for (int e = 0; e < E_; ++e) se += expf(g[e] - mx);
            const float lse = logf(se) + mx;
            float gl[E_], gmx = -1e30f, gmn = 1e30f;
            for (int e = 0; e < E_; ++e) { gl[e] = g[e] - lse; gmx = fmaxf(gmx, gl[e]); gmn = fminf(gmn, gl[e]); }
            for (int e = 0; e < E_; ++e) {
                if (lw[e] > 0.f)      gl[e] = gmx + 0.01f;
                else if (lw[e] < 0.f) gl[e] = gmn - 0.01f;
                g[e] = gl[e];
            }
        }

        float mx = -1e30f;
        #pragma unroll
        for (int e = 0; e < E_; ++e) mx = fmaxf(mx, g[e]);
        float p[E_];
        #pragma unroll
        for (int e = 0; e < E_; ++e) p[e] = expf(g[e] - mx);

        bool used[E_] = {};
        int   idx[TOPK];
        float twv[TOPK];
        float ssum = 0.f;
        for (int k = 0; k < TOPK; ++k) {
            int best = -1; float bv = -1e30f;
            for (int e = 0; e < E_; ++e)
                if (!used[e] && p[e] > bv) { bv = p[e]; best = e; }
            used[best] = true; idx[k] = best; twv[k] = bv; ssum += bv;
        }
        const float inv = 1.f / ssum;
        for (int k = 0; k < TOPK; ++k) {
            const int e = idx[k];
            const int slot = atomicAdd(&cnt[e], 1);
            tok_list[e * T_ + slot] = t;
            wgt_list[e * T_ + slot] = twv[k] * inv;
        }
    }
}

// ---------------------------------------------------------------------------
// Kernel 2: scan + tile table (wave-parallel).
// ---------------------------------------------------------------------------
__global__ void k_scan(const int* __restrict__ cnt, int* __restrict__ base,
                       int* __restrict__ tiln, int* __restrict__ tile_e,
                       int* __restrict__ tile_m0)
{
    const int lane = threadIdx.x;            // 64 threads, lanes 0..15 active
    int c = (lane < E_) ? cnt[lane] : 0;

    int s = c;
    #pragma unroll
    for (int off = 1; off < 16; off <<= 1) {
        int tv = __shfl_up(s, off);
        if ((lane & 15) >= off) s += tv;
    }
    if (lane < E_) base[lane] = s - c;
    if (lane == E_ - 1) base[E_] = s;

    int nt = (lane < E_) ? ((c + 63) >> 6) : 0;
    int ts = nt;
    #pragma unroll
    for (int off = 1; off < 16; off <<= 1) {
        int tv = __shfl_up(ts, off);
        if ((lane & 15) >= off) ts += tv;
    }
    if (lane == E_ - 1) tiln[0] = ts;
    if (lane < E_) {
        const int t0 = ts - nt;
        for (int i = 0; i < nt; ++i) {
            if (t0 + i < 96) { tile_e[t0 + i] = lane; tile_m0[t0 + i] = i * 64; }
        }
    }
}

// ---------------------------------------------------------------------------
// Repack: W [E][1024(k)][Ndim(n)] fp32 -> bf16 MFMA-fragment tiles.
// out[((e*(Ndim/16) + nb)*32 + kb)*512 + l*8 + j] = W[e][kb*32+(l>>4)*8+j][nb*16+(l&15)]
// ---------------------------------------------------------------------------
__global__ __launch_bounds__(256) void k_repack(
    const float* __restrict__ W, bf16* __restrict__ out, int Ndim)
{
    __shared__ float tile[32][260];
    const int e = blockIdx.z, kb = blockIdx.y, n0 = blockIdx.x * 256;
    const int t = threadIdx.x;
    const int nbs = Ndim >> 4;

    const float* src = W + ((size_t)e * 1024 + (size_t)kb * 32) * Ndim + n0;
    #pragma unroll
    for (int i = 0; i < 8; ++i) {
        const int idx = i * 256 + t;
        const int k = idx >> 6, c4 = (idx & 63) * 4;
        float4 v = *(const float4*)(src + (size_t)k * Ndim + c4);
        *(float4*)&tile[k][c4] = v;
    }
    __syncthreads();

    const int f = t >> 4;
    const int lg = (t & 15) * 4;
    bf16* dst = out + (((size_t)(e * nbs + n0 / 16 + f)) * 32 + kb) * 512;
    #pragma unroll
    for (int li = 0; li < 4; ++li) {
        const int l = lg + li, q = l >> 4, r = l & 15;
        bf16x8 p;
        #pragma unroll
        for (int j = 0; j < 8; ++j) p[j] = (bf16)tile[q * 8 + j][f * 16 + r];
        *(bf16x8*)(dst + l * 8) = p;
    }
}

// ---------------------------------------------------------------------------
// Kernel 3: grouped gate_up GEMM — NO LDS, NO BARRIERS. Both A and B are
// register-direct bf16x8 fragment loads (A from tB via token gather: 16 rows
// x 64B contiguous segments per b128; B from packed weights). Register
// double-buffer, 16 k-steps of 64. grid: (16, 80); wave w: gate nb = bx*4+w,
// up nb = gate+64.
// ---------------------------------------------------------------------------
__global__ __launch_bounds__(256) void k_gateup5(
    const bf16* __restrict__ tB, const bf16* __restrict__ w13p,
    const float* __restrict__ b13, const int* __restrict__ cnt,
    const int* __restrict__ base, const int* __restrict__ tiln,
    const int* __restrict__ tile_e, const int* __restrict__ tile_m0,
    const int* __restrict__ tok_list, bf16* __restrict__ act)
{
    const int ti = blockIdx.y;
    if (ti >= tiln[0]) return;
    const int e  = tile_e[ti];
    const int m0 = tile_m0[ti];
    const int ne = cnt[e];

    const int tid = threadIdx.x, lane = tid & 63, wave = tid >> 6;
    const int q = lane >> 4, r = lane & 15;

    // per-lane A row pointers: frag (mf,kc) elem j = tB[tok(m0+mf*16+r)][k0+kc*32+q*8+j]
    const bf16* pAr[4];
    #pragma unroll
    for (int mf = 0; mf < 4; ++mf) {
        int row = m0 + mf * 16 + r;
        row = row < ne ? row : ne - 1;
        pAr[mf] = tB + (size_t)tok_list[e * T_ + row] * H_ + q * 8;
    }

    const int nb_g = blockIdx.x * 4 + wave;
    const bf16* pBg = w13p + ((size_t)(e * 128 + nb_g     ) * 32) * 512 + lane * 8;
    const bf16* pBu = w13p + ((size_t)(e * 128 + nb_g + 64) * 32) * 512 + lane * 8;

    f32x4 accg[4] = {};
    f32x4 accu[4] = {};
    bf16x8 a0[4][2], a1[4][2], bg0[2], bu0[2], bg1[2], bu1[2];

#define LOADS(AF, BG, BU, K0) do { \
    _Pragma("unroll") \
    for (int mf = 0; mf < 4; ++mf) { \
        AF[mf][0] = *(const bf16x8*)(pAr[mf] + (K0)); \
        AF[mf][1] = *(const bf16x8*)(pAr[mf] + (K0) + 32); \
    } \
    BG[0] = *(const bf16x8*)pBg; BG[1] = *(const bf16x8*)(pBg + 512); pBg += 1024; \
    BU[0] = *(const bf16x8*)pBu; BU[1] = *(const bf16x8*)(pBu + 512); pBu += 1024; \
} while (0)

#define COMPUTE(AF, BG, BU) do { \
    _Pragma("unroll") \
    for (int kc = 0; kc < 2; ++kc) \
        _Pragma("unroll") \
        for (int mf = 0; mf < 4; ++mf) { \
            accg[mf] = __builtin_amdgcn_mfma_f32_16x16x32_bf16(AF[mf][kc], BG[kc], accg[mf], 0, 0, 0); \
            accu[mf] = __builtin_amdgcn_mfma_f32_16x16x32_bf16(AF[mf][kc], BU[kc], accu[mf], 0, 0, 0); \
        } \
} while (0)

    LOADS(a0, bg0, bu0, 0);
    #pragma unroll 1
    for (int t = 0; t < 7; ++t) {
        LOADS(a1, bg1, bu1, 64);
        COMPUTE(a0, bg0, bu0);
        LOADS(a0, bg0, bu0, 128);
        COMPUTE(a1, bg1, bu1);
        pAr[0] += 128; pAr[1] += 128; pAr[2] += 128; pAr[3] += 128;
    }
    LOADS(a1, bg1, bu1, 64);          // final step k=960
    COMPUTE(a0, bg0, bu0);
    COMPUTE(a1, bg1, bu1);
#undef LOADS
#undef COMPUTE

    // --- epilogue ---
    const int sb = base[e];
    const int cg = nb_g * 16 + r;
    const float bgv = b13[e * 2 * IDIM + cg];
    const float buv = b13[e * 2 * IDIM + IDIM + cg];
    #pragma unroll
    for (int mf = 0; mf < 4; ++mf) {
        #pragma unroll
        for (int rg = 0; rg < 4; ++rg) {
            const int row = mf * 16 + q * 4 + rg;
            if (m0 + row < ne) {
                const float hg = accg[mf][rg] + bgv;
                const float hu = accu[mf][rg] + buv;
                const float gt = fminf(hg, LIMIT);
                const float up = fminf(fmaxf(hu, -LIMIT), LIMIT);
                const float av = (up + 1.0f) * gt / (1.0f + expf(-ALPHA * gt));
                act[(size_t)(sb + m0 + row) * IDIM + cg] = (bf16)av;
            }
        }
    }
}

// ---------------------------------------------------------------------------
// Kernel 4: grouped down GEMM + weighted atomic combine — NO LDS/barriers,
// register-direct A (contiguous expert rows) and packed B.
// grid: (8, 80); wave w: nb = bx*8 + w*2 + {0,1}.
// ---------------------------------------------------------------------------
__global__ __launch_bounds__(256) void k_down5(
    const bf16* __restrict__ act, const bf16* __restrict__ w2p,
    const float* __restrict__ b2, const int* __restrict__ cnt,
    const int* __restrict__ base, const int* __restrict__ tiln,
    const int* __restrict__ tile_e, const int* __restrict__ tile_m0,
    const int* __restrict__ tok_list, const float* __restrict__ wgt_list,
    float* __restrict__ out)
{
    const int ti = blockIdx.y;
    if (ti >= tiln[0]) return;
    const int e  = tile_e[ti];
    const int m0 = tile_m0[ti];
    const int ne = cnt[e];
    const int sb = base[e];

    const int tid = threadIdx.x, lane = tid & 63, wave = tid >> 6;
    const int q = lane >> 4, r = lane & 15;

    const bf16* pAr[4];
    #pragma unroll
    for (int mf = 0; mf < 4; ++mf) {
        int row = m0 + mf * 16 + r;
        row = row < ne ? row : ne - 1;
        pAr[mf] = act + (size_t)(sb + row) * IDIM + q * 8;
    }

    const int nb0 = blockIdx.x * 8 + wave * 2;
    const bf16* pB0 = w2p + ((size_t)(e * 64 + nb0    ) * 32) * 512 + lane * 8;
    const bf16* pB1 = w2p + ((size_t)(e * 64 + nb0 + 1) * 32) * 512 + lane * 8;

    f32x4 acc[4][2] = {};
    bf16x8 a0[4][2], a1[4][2], c0[2], d0[2], c1[2], d1[2];

#define LOADS(AF, B0, B1, K0) do { \
    _Pragma("unroll") \
    for (int mf = 0; mf < 4; ++mf) { \
        AF[mf][0] = *(const bf16x8*)(pAr[mf] + (K0)); \
        AF[mf][1] = *(const bf16x8*)(pAr[mf] + (K0) + 32); \
    } \
    B0[0] = *(const bf16x8*)pB0; B0[1] = *(const bf16x8*)(pB0 + 512); pB0 += 1024; \
    B1[0] = *(const bf16x8*)pB1; B1[1] = *(const bf16x8*)(pB1 + 512); pB1 += 1024; \
} while (0)

#define COMPUTE(AF, B0, B1) do { \
    _Pragma("unroll") \
    for (int kc = 0; kc < 2; ++kc) \
        _Pragma("unroll") \
        for (int mf = 0; mf < 4; ++mf) { \
            acc[mf][0] = __builtin_amdgcn_mfma_f32_16x16x32_bf16(AF[mf][kc], B0[kc], acc[mf][0], 0, 0, 0); \
            acc[mf][1] = __builtin_amdgcn_mfma_f32_16x16x32_bf16(AF[mf][kc], B1[kc], acc[mf][1], 0, 0, 0); \
        } \
} while (0)

    LOADS(a0, c0, d0, 0);
    #pragma unroll 1
    for (int t = 0; t < 7; ++t) {
        LOADS(a1, c1, d1, 64);
        COMPUTE(a0, c0, d0);
        LOADS(a0, c0, d0, 128);
        COMPUTE(a1, c1, d1);
        pAr[0] += 128; pAr[1] += 128; pAr[2] += 128; pAr[3] += 128;
    }
    LOADS(a1, c1, d1, 64);
    COMPUTE(a0, c0, d0);
    COMPUTE(a1, c1, d1);
#undef LOADS
#undef COMPUTE

    #pragma unroll
    for (int nf = 0; nf < 2; ++nf) {
        const int ch = (nb0 + nf) * 16 + r;
        const float bb = b2[e * H_ + ch];
        #pragma unroll
        for (int mf = 0; mf < 4; ++mf) {
            #pragma unroll
            for (int rg = 0; rg < 4; ++rg) {
                const int row = mf * 16 + q * 4 + rg;
                const int s = m0 + row;
                if (s < ne) {
                    const int   tok = tok_list[e * T_ + s];
                    const float w   = wgt_list[e * T_ + s];
                    atomicAdd(&out[(size_t)tok * H_ + ch], w * (acc[mf][nf][rg] + bb));
                }
            }
        }
    }
}

// ---------------------------------------------------------------------------
// Fallback (round-1) GEMMs, used if ws too small for packed weights.
// ---------------------------------------------------------------------------
__global__ __launch_bounds__(256) void k_gateup(
    const bf16* __restrict__ tB, const float* __restrict__ w13,
    const float* __restrict__ b13, const int* __restrict__ cnt,
    const int* __restrict__ base, const int* __restrict__ tok_list,
    bf16* __restrict__ act)
{
    const int e  = blockIdx.z;
    const int ne = cnt[e];
    const int m0 = blockIdx.y * 64;
    if (m0 >= ne) return;
    const int n0  = blockIdx.x * 64;
    const int tid = threadIdx.x, lane = tid & 63, wave = tid >> 6;

    __shared__ __align__(16) bf16 As[64][40];
    __shared__ __align__(16) bf16 Bg[64][40];
    __shared__ __align__(16) bf16 Bu[64][40];
    __shared__ int stok[64];

    if (tid < 64) {
        const int s = m0 + tid;
        stok[tid] = (s < ne) ? tok_list[e * T_ + s] : -1;
    }
    __syncthreads();

    const int ar = tid >> 2, ak = (tid & 3) * 8;
    const int atok = stok[ar];
    const int bn = tid & 63, bk = wave * 8;
    const size_t wrow = (size_t)(2 * IDIM);
    const float* wbase = w13 + (size_t)e * H_ * wrow + n0 + bn;

    const int wm = wave >> 1, wn = wave & 1;
    const int q = lane >> 4, r = lane & 15;
    f32x4 accg[2][2] = {};
    f32x4 accu[2][2] = {};

    for (int kb = 0; kb < H_ / 32; ++kb) {
        __syncthreads();
        uint4 av = make_uint4(0u, 0u, 0u, 0u);
        if (atok >= 0)
            av = *(const uint4*)(tB + (size_t)atok * H_ + kb * 32 + ak);
        *(uint4*)&As[ar][ak] = av;
        {
            const float* src = wbase + (size_t)(kb * 32 + bk) * wrow;
            bf16x8 pg, pu;
            #pragma unroll
            for (int j = 0; j < 8; ++j) {
                pg[j] = (bf16)src[(size_t)j * wrow];
                pu[j] = (bf16)src[(size_t)j * wrow + IDIM];
            }
            *(bf16x8*)&Bg[bn][bk] = pg;
            *(bf16x8*)&Bu[bn][bk] = pu;
        }
        __syncthreads();
        bf16x8 a[2], bg[2], bu[2];
        a[0]  = *(const bf16x8*)&As[wm * 32 +      r][q * 8];
        a[1]  = *(const bf16x8*)&As[wm * 32 + 16 + r][q * 8];
        bg[0] = *(const bf16x8*)&Bg[wn * 32 +      r][q * 8];
        bg[1] = *(const bf16x8*)&Bg[wn * 32 + 16 + r][q * 8];
        bu[0] = *(const bf16x8*)&Bu[wn * 32 +      r][q * 8];
        bu[1] = *(const bf16x8*)&Bu[wn * 32 + 16 + r][q * 8];
        #pragma unroll
        for (int im = 0; im < 2; ++im)
            #pragma unroll
            for (int in = 0; in < 2; ++in) {
                accg[im][in] = __builtin_amdgcn_mfma_f32_16x16x32_bf16(a[im], bg[in], accg[im][in], 0, 0, 0);
                accu[im][in] = __builtin_amdgcn_mfma_f32_16x16x32_bf16(a[im], bu[in], accu[im][in], 0, 0, 0);
            }
    }

    const int sb = base[e];
    #pragma unroll
    for (int im = 0; im < 2; ++im)
        #pragma unroll
        for (int in = 0; in < 2; ++in)
            #pragma unroll
            for (int rg = 0; rg < 4; ++rg) {
                const int row = wm * 32 + im * 16 + q * 4 + rg;
                const int col = wn * 32 + in * 16 + r;
                if (m0 + row < ne) {
                    const float hg = accg[im][in][rg] + b13[e * 2 * IDIM + n0 + col];
                    const float hu = accu[im][in][rg] + b13[e * 2 * IDIM + IDIM + n0 + col];
                    const float gt = fminf(hg, LIMIT);
                    const float up = fminf(fmaxf(hu, -LIMIT), LIMIT);
                    const float av = (up + 1.0f) * gt / (1.0f + expf(-ALPHA * gt));
                    act[(size_t)(sb + m0 + row) * IDIM + n0 + col] = (bf16)av;
                }
            }
}

__global__ __launch_bounds__(256) void k_down(
    const bf16* __restrict__ act, const float* __restrict__ w2,
    const float* __restrict__ b2, const int* __restrict__ cnt,
    const int* __restrict__ base, const int* __restrict__ tok_list,
    const float* __restrict__ wgt_list, float* __restrict__ out)
{
    const int e  = blockIdx.z;
    const int ne = cnt[e];
    const int m0 = blockIdx.y * 64;
    if (m0 >= ne) return;
    const int n0  = blockIdx.x * 64;
    const int tid = threadIdx.x, lane = tid & 63, wave = tid >> 6;

    __shared__ __align__(16) bf16 As[64][40];
    __shared__ __align__(16) bf16 Bs[64][40];
    __shared__ int   stok[64];
    __shared__ float swgt[64];

    if (tid < 64) {
        const int s = m0 + tid;
        stok[tid] = (s < ne) ? tok_list[e * T_ + s] : -1;
        swgt[tid] = (s < ne) ? wgt_list[e * T_ + s] : 0.f;
    }
    __syncthreads();

    const int sb = base[e];
    const int ar = tid >> 2, ak = (tid & 3) * 8;
    const bool arow_ok = (m0 + ar) < ne;
    const int bn = tid & 63, bk = wave * 8;
    const float* wbase = w2 + (size_t)e * IDIM * H_ + n0 + bn;

    const int wm = wave >> 1, wn = wave & 1;
    const int q = lane >> 4, r = lane & 15;
    f32x4 acc[2][2] = {};

    for (int kb = 0; kb < IDIM / 32; ++kb) {
        __syncthreads();
        uint4 av = make_uint4(0u, 0u, 0u, 0u);
        if (arow_ok)
            av = *(const uint4*)(act + (size_t)(sb + m0 + ar) * IDIM + kb * 32 + ak);
        *(uint4*)&As[ar][ak] = av;
        {
            const float* src = wbase + (size_t)(kb * 32 + bk) * H_;
            bf16x8 pb;
            #pragma unroll
            for (int j = 0; j < 8; ++j) pb[j] = (bf16)src[(size_t)j * H_];
            *(bf16x8*)&Bs[bn][bk] = pb;
        }
        __syncthreads();
        bf16x8 a[2], b[2];
        a[0] = *(const bf16x8*)&As[wm * 32 +      r][q * 8];
        a[1] = *(const bf16x8*)&As[wm * 32 + 16 + r][q * 8];
        b[0] = *(const bf16x8*)&Bs[wn * 32 +      r][q * 8];
        b[1] = *(const bf16x8*)&Bs[wn * 32 + 16 + r][q * 8];
        #pragma unroll
        for (int im = 0; im < 2; ++im)
            #pragma unroll
            for (int in = 0; in < 2; ++in)
                acc[im][in] = __builtin_amdgcn_mfma_f32_16x16x32_bf16(a[im], b[in], acc[im][in], 0, 0, 0);
    }

    #pragma unroll
    for (int im = 0; im < 2; ++im)
        #pragma unroll
        for (int in = 0; in < 2; ++in)
            #pragma unroll
            for (int rg = 0; rg < 4; ++rg) {
                const int row = wm * 32 + im * 16 + q * 4 + rg;
                const int col = wn * 32 + in * 16 + r;
                if (m0 + row < ne) {
                    const int   tok = stok[row];
                    const float w   = swgt[row];
                    atomicAdd(&out[(size_t)tok * H_ + n0 + col], w * (acc[im][in][rg] + b2[e * H_ + n0 + col]));
                }
            }
}

// ---------------------------------------------------------------------------
extern "C" void kernel_launch(void* const* d_in, const int* in_sizes, int n_in,
                              void* d_out, int out_size, void* d_ws, size_t ws_size,
                              hipStream_t stream)
{
    const float* x        = (const float*)d_in[0];
    const float* norm_w   = (const float*)d_in[1];
    const float* router_w = (const float*)d_in[2];
    const float* router_b = (const float*)d_in[3];
    const float* w13      = (const float*)d_in[4];
    const float* b13      = (const float*)d_in[5];
    const float* w2       = (const float*)d_in[6];
    const float* b2       = (const float*)d_in[7];
    const float* manual_w = (const float*)d_in[8];
    const int*   layer_i  = (const int*)d_in[9];
    float* out = (float*)d_out;

    char* ws = (char*)d_ws;
    bf16*  tB   = (bf16*)ws;                              // 2 MB @ 0
    bf16*  act  = (bf16*)(ws + (2ull << 20));             // 8 MB @ 2M
    char*  meta = ws + (10ull << 20);
    int*   cnt      = (int*)meta;                         // 16 ints
    int*   basep    = (int*)(meta + 64);                  // 17 ints
    int*   tiln     = (int*)(meta + 256);                 // 1 int
    int*   tile_e   = (int*)(meta + 512);                 // 96 ints
    int*   tile_m0  = (int*)(meta + 1024);                // 96 ints
    int*   tok_list = (int*)(meta + (16ull << 10));       // 64 KB
    float* wgt_list = (float*)(meta + (16ull << 10) + (64ull << 10)); // 64 KB
    bf16*  w13p     = (bf16*)(ws + (12ull << 20));        // 64 MB
    bf16*  w2p      = (bf16*)(ws + (76ull << 20));        // 32 MB

    const bool fast = ws_size >= (108ull << 20);

    hipMemsetAsync(cnt, 0, E_ * sizeof(int), stream);

    k_rms_router<<<T_, 256, 0, stream>>>(x, norm_w, router_w, router_b,
                                         manual_w, layer_i, tB, out,
                                         cnt, tok_list, wgt_list);
    k_scan<<<1, 64, 0, stream>>>(cnt, basep, tiln, tile_e, tile_m0);

    if (fast) {
        dim3 gr13(2 * IDIM / 256, 32, E_);
        k_repack<<<gr13, 256, 0, stream>>>(w13, w13p, 2 * IDIM);
        dim3 gr2(H_ / 256, 32, E_);
        k_repack<<<gr2, 256, 0, stream>>>(w2, w2p, H_);

        dim3 gg(16, 80);
        k_gateup5<<<gg, 256, 0, stream>>>(tB, w13p, b13, cnt, basep, tiln,
                                          tile_e, tile_m0, tok_list, act);
        dim3 gd(8, 80);
        k_down5<<<gd, 256, 0, stream>>>(act, w2p, b2, cnt, basep, tiln,
                                        tile_e, tile_m0, tok_list, wgt_list, out);
    } else {
        dim3 gg(IDIM / 64, T_ / 64, E_);
        k_gateup<<<gg, 256, 0, stream>>>(tB, w13, b13, cnt, basep, tok_list, act);
        dim3 gd(H_ / 64, T_ / 64, E_);
        k_down<<<gd, 256, 0, stream>>>(act, w2, b2, cnt, basep, tok_list, wgt_list, out);
    }
}

// Round 3
// 474.174 us; speedup vs baseline: 1.0107x; 1.0107x over previous
//
#include <hip/hip_runtime.h>

#define T_    1024
#define H_    1024
#define IDIM  1024
#define E_    16
#define TOPK  4
#define ALPHA 1.702f
#define LIMIT 7.0f

typedef __bf16 bf16;
typedef __bf16 bf16x4 __attribute__((ext_vector_type(4)));
typedef __bf16 bf16x8 __attribute__((ext_vector_type(8)));
typedef float  f32x4  __attribute__((ext_vector_type(4)));

// ---------------------------------------------------------------------------
// Kernel 1: RMSNorm + router logits + softmax/top-4 + routing lists.
// ---------------------------------------------------------------------------
__global__ __launch_bounds__(256) void k_rms_router(
    const float* __restrict__ x, const float* __restrict__ nw,
    const float* __restrict__ rw, const float* __restrict__ rb,
    const float* __restrict__ mw, const int* __restrict__ lidx,
    bf16* __restrict__ tB, float* __restrict__ out,
    int* __restrict__ cnt, int* __restrict__ tok_list,
    float* __restrict__ wgt_list)
{
    const int t = blockIdx.x, tid = threadIdx.x;
    const int lane = tid & 63, wave = tid >> 6;
    __shared__ float tbuf[H_];
    __shared__ float red[4];
    __shared__ float logits[E_];

    float4 xv = ((const float4*)(x + (size_t)t * H_))[tid];
    float4 wv = ((const float4*)nw)[tid];
    float ssq = xv.x*xv.x + xv.y*xv.y + xv.z*xv.z + xv.w*xv.w;
    #pragma unroll
    for (int off = 32; off; off >>= 1) ssq += __shfl_xor(ssq, off);
    if (lane == 0) red[wave] = ssq;
    __syncthreads();
    const float rms = rsqrtf((red[0] + red[1] + red[2] + red[3]) * (1.0f / H_) + 1e-5f);

    float4 tv;
    tv.x = xv.x * rms * wv.x;
    tv.y = xv.y * rms * wv.y;
    tv.z = xv.z * rms * wv.z;
    tv.w = xv.w * rms * wv.w;

    ((float4*)(out + (size_t)t * H_))[tid] = xv;      // residual init
    ((float4*)tbuf)[tid] = tv;
    bf16x4 tb = { (bf16)tv.x, (bf16)tv.y, (bf16)tv.z, (bf16)tv.w };
    *(bf16x4*)(tB + (size_t)t * H_ + tid * 4) = tb;
    __syncthreads();

    #pragma unroll
    for (int ei = 0; ei < 4; ++ei) {
        const int e = wave * 4 + ei;
        const float* wr = rw + (size_t)e * H_;
        float s = 0.f;
        #pragma unroll
        for (int j = 0; j < 16; ++j) {
            const int c = lane + j * 64;
            s += tbuf[c] * wr[c];
        }
        #pragma unroll
        for (int off = 32; off; off >>= 1) s += __shfl_xor(s, off);
        if (lane == 0) logits[e] = s + rb[e];
    }
    __syncthreads();

    if (tid == 0) {
        float g[E_];
        #pragma unroll
        for (int e = 0; e < E_; ++e) g[e] = logits[e];

        const int li = lidx[0];
        float ma = 0.f, lw[E_];
        #pragma unroll
        for (int e = 0; e < E_; ++e) { lw[e] = mw[li * E_ + e]; ma = fmaxf(ma, fabsf(lw[e])); }
        if (ma > 0.f) {
            float mx = -1e30f;
            for (int e = 0; e < E_; ++e) mx = fmaxf(mx, g[e]);
            float se = 0.f;
            for (int e = 0; e < E_; ++e) se += expf(g[e] - mx);
            const float lse = logf(se) + mx;
            float gl[E_], gmx = -1e30f, gmn = 1e30f;
            for (int e = 0; e < E_; ++e) { gl[e] = g[e] - lse; gmx = fmaxf(gmx, gl[e]); gmn = fminf(gmn, gl[e]); }
            for (int e = 0; e < E_; ++e) {
                if (lw[e] > 0.f)      gl[e] = gmx + 0.01f;
                else if (lw[e] < 0.f) gl[e] = gmn - 0.01f;
                g[e] = gl[e];
            }
        }

        float mx = -1e30f;
        #pragma unroll
        for (int e = 0; e < E_; ++e) mx = fmaxf(mx, g[e]);
        float p[E_];
        #pragma unroll
        for (int e = 0; e < E_; ++e) p[e] = expf(g[e] - mx);

        bool used[E_] = {};
        int   idx[TOPK];
        float twv[TOPK];
        float ssum = 0.f;
        for (int k = 0; k < TOPK; ++k) {
            int best = -1; float bv = -1e30f;
            for (int e = 0; e < E_; ++e)
                if (!used[e] && p[e] > bv) { bv = p[e]; best = e; }
            used[best] = true; idx[k] = best; twv[k] = bv; ssum += bv;
        }
        const float inv = 1.f / ssum;
        for (int k = 0; k < TOPK; ++k) {
            const int e = idx[k];
            const int slot = atomicAdd(&cnt[e], 1);
            tok_list[e * T_ + slot] = t;
            wgt_list[e * T_ + slot] = twv[k] * inv;
        }
    }
}

// ---------------------------------------------------------------------------
// Kernel 2: scan + tile table (wave-parallel).
// ---------------------------------------------------------------------------
__global__ void k_scan(const int* __restrict__ cnt, int* __restrict__ base,
                       int* __restrict__ tiln, int* __restrict__ tile_e,
                       int* __restrict__ tile_m0)
{
    const int lane = threadIdx.x;            // 64 threads, lanes 0..15 active
    int c = (lane < E_) ? cnt[lane] : 0;

    int s = c;
    #pragma unroll
    for (int off = 1; off < 16; off <<= 1) {
        int tv = __shfl_up(s, off);
        if ((lane & 15) >= off) s += tv;
    }
    if (lane < E_) base[lane] = s - c;
    if (lane == E_ - 1) base[E_] = s;

    int nt = (lane < E_) ? ((c + 63) >> 6) : 0;
    int ts = nt;
    #pragma unroll
    for (int off = 1; off < 16; off <<= 1) {
        int tv = __shfl_up(ts, off);
        if ((lane & 15) >= off) ts += tv;
    }
    if (lane == E_ - 1) tiln[0] = ts;
    if (lane < E_) {
        const int t0 = ts - nt;
        for (int i = 0; i < nt; ++i) {
            if (t0 + i < 96) { tile_e[t0 + i] = lane; tile_m0[t0 + i] = i * 64; }
        }
    }
}

// ---------------------------------------------------------------------------
// Repack: W [E][1024(k)][Ndim(n)] fp32 -> bf16 MFMA-fragment tiles.
// out[((e*(Ndim/16) + nb)*32 + kb)*512 + l*8 + j] = W[e][kb*32+(l>>4)*8+j][nb*16+(l&15)]
// ---------------------------------------------------------------------------
__global__ __launch_bounds__(256) void k_repack(
    const float* __restrict__ W, bf16* __restrict__ out, int Ndim)
{
    __shared__ float tile[32][260];
    const int e = blockIdx.z, kb = blockIdx.y, n0 = blockIdx.x * 256;
    const int t = threadIdx.x;
    const int nbs = Ndim >> 4;

    const float* src = W + ((size_t)e * 1024 + (size_t)kb * 32) * Ndim + n0;
    #pragma unroll
    for (int i = 0; i < 8; ++i) {
        const int idx = i * 256 + t;
        const int k = idx >> 6, c4 = (idx & 63) * 4;
        float4 v = *(const float4*)(src + (size_t)k * Ndim + c4);
        *(float4*)&tile[k][c4] = v;
    }
    __syncthreads();

    const int f = t >> 4;
    const int lg = (t & 15) * 4;
    bf16* dst = out + (((size_t)(e * nbs + n0 / 16 + f)) * 32 + kb) * 512;
    #pragma unroll
    for (int li = 0; li < 4; ++li) {
        const int l = lg + li, q = l >> 4, r = l & 15;
        bf16x8 p;
        #pragma unroll
        for (int j = 0; j < 8; ++j) p[j] = (bf16)tile[q * 8 + j][f * 16 + r];
        *(bf16x8*)(dst + l * 8) = p;
    }
}

// ---------------------------------------------------------------------------
// Kernel 3: grouped gate_up GEMM — NO LDS/barriers, register-direct A and
// packed B, explicit fully-unrolled 16-step software pipeline:
// B (slow L3/HBM stream) prefetched 2 steps ahead (3 buffers), A (L2-hot)
// 1 step ahead (2 buffers). __launch_bounds__(256,2) gives the register
// budget (~170 VGPR) the pipeline needs — at the default budget (64 VGPR)
// the compiler collapses the pipeline and exposes full load latency.
// grid: (16, 80); wave w: gate nb = bx*4+w, up nb = gate+64.
// ---------------------------------------------------------------------------
__global__ __launch_bounds__(256, 2) void k_gateup6(
    const bf16* __restrict__ tB, const bf16* __restrict__ w13p,
    const float* __restrict__ b13, const int* __restrict__ cnt,
    const int* __restrict__ base, const int* __restrict__ tiln,
    const int* __restrict__ tile_e, const int* __restrict__ tile_m0,
    const int* __restrict__ tok_list, bf16* __restrict__ act)
{
    const int ti = blockIdx.y;
    if (ti >= tiln[0]) return;
    const int e  = tile_e[ti];
    const int m0 = tile_m0[ti];
    const int ne = cnt[e];

    const int tid = threadIdx.x, lane = tid & 63, wave = tid >> 6;
    const int q = lane >> 4, r = lane & 15;

    // per-lane A row pointers: frag (mf,kc) elem j = tB[tok(m0+mf*16+r)][s*64+kc*32+q*8+j]
    const bf16* pAr[4];
    #pragma unroll
    for (int mf = 0; mf < 4; ++mf) {
        int row = m0 + mf * 16 + r;
        row = row < ne ? row : ne - 1;
        pAr[mf] = tB + (size_t)tok_list[e * T_ + row] * H_ + q * 8;
    }

    const int nb_g = blockIdx.x * 4 + wave;
    const bf16* pBg = w13p + ((size_t)(e * 128 + nb_g     ) * 32) * 512 + lane * 8;
    const bf16* pBu = w13p + ((size_t)(e * 128 + nb_g + 64) * 32) * 512 + lane * 8;

    f32x4 accg[4] = {};
    f32x4 accu[4] = {};
    bf16x8 A[2][4][2];
    bf16x8 BG[3][2], BU[3][2];

#define ALOAD(buf, s) do { \
    _Pragma("unroll") \
    for (int mf = 0; mf < 4; ++mf) { \
        buf[mf][0] = *(const bf16x8*)(pAr[mf] + (s) * 64); \
        buf[mf][1] = *(const bf16x8*)(pAr[mf] + (s) * 64 + 32); \
    } } while (0)
#define BLOAD(bg, bu, s) do { \
    bg[0] = *(const bf16x8*)(pBg + (size_t)(s) * 1024); \
    bg[1] = *(const bf16x8*)(pBg + (size_t)(s) * 1024 + 512); \
    bu[0] = *(const bf16x8*)(pBu + (size_t)(s) * 1024); \
    bu[1] = *(const bf16x8*)(pBu + (size_t)(s) * 1024 + 512); } while (0)
#define COMPUTE(AF, bg, bu) do { \
    _Pragma("unroll") \
    for (int kc = 0; kc < 2; ++kc) \
        _Pragma("unroll") \
        for (int mf = 0; mf < 4; ++mf) { \
            accg[mf] = __builtin_amdgcn_mfma_f32_16x16x32_bf16(AF[mf][kc], bg[kc], accg[mf], 0, 0, 0); \
            accu[mf] = __builtin_amdgcn_mfma_f32_16x16x32_bf16(AF[mf][kc], bu[kc], accu[mf], 0, 0, 0); \
        } } while (0)

    BLOAD(BG[0], BU[0], 0);
    BLOAD(BG[1], BU[1], 1);
    ALOAD(A[0], 0);
    #pragma unroll
    for (int t = 0; t < 16; ++t) {
        const int sb_ = (t + 2 < 16) ? t + 2 : 15;   // clamped: no OOB prefetch
        const int sa_ = (t + 1 < 16) ? t + 1 : 15;
        BLOAD(BG[(t + 2) % 3], BU[(t + 2) % 3], sb_);
        ALOAD(A[(t + 1) & 1], sa_);
        COMPUTE(A[t & 1], BG[t % 3], BU[t % 3]);
    }
#undef ALOAD
#undef BLOAD
#undef COMPUTE

    // --- epilogue ---
    const int sb = base[e];
    const int cg = nb_g * 16 + r;
    const float bgv = b13[e * 2 * IDIM + cg];
    const float buv = b13[e * 2 * IDIM + IDIM + cg];
    #pragma unroll
    for (int mf = 0; mf < 4; ++mf) {
        #pragma unroll
        for (int rg = 0; rg < 4; ++rg) {
            const int row = mf * 16 + q * 4 + rg;
            if (m0 + row < ne) {
                const float hg = accg[mf][rg] + bgv;
                const float hu = accu[mf][rg] + buv;
                const float gt = fminf(hg, LIMIT);
                const float up = fminf(fmaxf(hu, -LIMIT), LIMIT);
                const float av = (up + 1.0f) * gt / (1.0f + expf(-ALPHA * gt));
                act[(size_t)(sb + m0 + row) * IDIM + cg] = (bf16)av;
            }
        }
    }
}

// ---------------------------------------------------------------------------
// Kernel 4: grouped down GEMM + weighted atomic combine — same pipelined
// structure. grid: (8, 80); wave w: nb = bx*8 + w*2 + {0,1}.
// ---------------------------------------------------------------------------
__global__ __launch_bounds__(256, 2) void k_down6(
    const bf16* __restrict__ act, const bf16* __restrict__ w2p,
    const float* __restrict__ b2, const int* __restrict__ cnt,
    const int* __restrict__ base, const int* __restrict__ tiln,
    const int* __restrict__ tile_e, const int* __restrict__ tile_m0,
    const int* __restrict__ tok_list, const float* __restrict__ wgt_list,
    float* __restrict__ out)
{
    const int ti = blockIdx.y;
    if (ti >= tiln[0]) return;
    const int e  = tile_e[ti];
    const int m0 = tile_m0[ti];
    const int ne = cnt[e];
    const int sb = base[e];

    const int tid = threadIdx.x, lane = tid & 63, wave = tid >> 6;
    const int q = lane >> 4, r = lane & 15;

    const bf16* pAr[4];
    #pragma unroll
    for (int mf = 0; mf < 4; ++mf) {
        int row = m0 + mf * 16 + r;
        row = row < ne ? row : ne - 1;
        pAr[mf] = act + (size_t)(sb + row) * IDIM + q * 8;
    }

    const int nb0 = blockIdx.x * 8 + wave * 2;
    const bf16* pB0 = w2p + ((size_t)(e * 64 + nb0    ) * 32) * 512 + lane * 8;
    const bf16* pB1 = w2p + ((size_t)(e * 64 + nb0 + 1) * 32) * 512 + lane * 8;

    f32x4 acc[4][2] = {};
    bf16x8 A[2][4][2];
    bf16x8 B0[3][2], B1[3][2];

#define ALOAD(buf, s) do { \
    _Pragma("unroll") \
    for (int mf = 0; mf < 4; ++mf) { \
        buf[mf][0] = *(const bf16x8*)(pAr[mf] + (s) * 64); \
        buf[mf][1] = *(const bf16x8*)(pAr[mf] + (s) * 64 + 32); \
    } } while (0)
#define BLOAD(b0, b1, s) do { \
    b0[0] = *(const bf16x8*)(pB0 + (size_t)(s) * 1024); \
    b0[1] = *(const bf16x8*)(pB0 + (size_t)(s) * 1024 + 512); \
    b1[0] = *(const bf16x8*)(pB1 + (size_t)(s) * 1024); \
    b1[1] = *(const bf16x8*)(pB1 + (size_t)(s) * 1024 + 512); } while (0)
#define COMPUTE(AF, b0, b1) do { \
    _Pragma("unroll") \
    for (int kc = 0; kc < 2; ++kc) \
        _Pragma("unroll") \
        for (int mf = 0; mf < 4; ++mf) { \
            acc[mf][0] = __builtin_amdgcn_mfma_f32_16x16x32_bf16(AF[mf][kc], b0[kc], acc[mf][0], 0, 0, 0); \
            acc[mf][1] = __builtin_amdgcn_mfma_f32_16x16x32_bf16(AF[mf][kc], b1[kc], acc[mf][1], 0, 0, 0); \
        } } while (0)

    BLOAD(B0[0], B1[0], 0);
    BLOAD(B0[1], B1[1], 1);
    ALOAD(A[0], 0);
    #pragma unroll
    for (int t = 0; t < 16; ++t) {
        const int sb_ = (t + 2 < 16) ? t + 2 : 15;
        const int sa_ = (t + 1 < 16) ? t + 1 : 15;
        BLOAD(B0[(t + 2) % 3], B1[(t + 2) % 3], sb_);
        ALOAD(A[(t + 1) & 1], sa_);
        COMPUTE(A[t & 1], B0[t % 3], B1[t % 3]);
    }
#undef ALOAD
#undef BLOAD
#undef COMPUTE

    #pragma unroll
    for (int nf = 0; nf < 2; ++nf) {
        const int ch = (nb0 + nf) * 16 + r;
        const float bb = b2[e * H_ + ch];
        #pragma unroll
        for (int mf = 0; mf < 4; ++mf) {
            #pragma unroll
            for (int rg = 0; rg < 4; ++rg) {
                const int row = mf * 16 + q * 4 + rg;
                const int s = m0 + row;
                if (s < ne) {
                    const int   tok = tok_list[e * T_ + s];
                    const float w   = wgt_list[e * T_ + s];
                    atomicAdd(&out[(size_t)tok * H_ + ch], w * (acc[mf][nf][rg] + bb));
                }
            }
        }
    }
}

// ---------------------------------------------------------------------------
// Fallback (round-1) GEMMs, used if ws too small for packed weights.
// ---------------------------------------------------------------------------
__global__ __launch_bounds__(256) void k_gateup(
    const bf16* __restrict__ tB, const float* __restrict__ w13,
    const float* __restrict__ b13, const int* __restrict__ cnt,
    const int* __restrict__ base, const int* __restrict__ tok_list,
    bf16* __restrict__ act)
{
    const int e  = blockIdx.z;
    const int ne = cnt[e];
    const int m0 = blockIdx.y * 64;
    if (m0 >= ne) return;
    const int n0  = blockIdx.x * 64;
    const int tid = threadIdx.x, lane = tid & 63, wave = tid >> 6;

    __shared__ __align__(16) bf16 As[64][40];
    __shared__ __align__(16) bf16 Bg[64][40];
    __shared__ __align__(16) bf16 Bu[64][40];
    __shared__ int stok[64];

    if (tid < 64) {
        const int s = m0 + tid;
        stok[tid] = (s < ne) ? tok_list[e * T_ + s] : -1;
    }
    __syncthreads();

    const int ar = tid >> 2, ak = (tid & 3) * 8;
    const int atok = stok[ar];
    const int bn = tid & 63, bk = wave * 8;
    const size_t wrow = (size_t)(2 * IDIM);
    const float* wbase = w13 + (size_t)e * H_ * wrow + n0 + bn;

    const int wm = wave >> 1, wn = wave & 1;
    const int q = lane >> 4, r = lane & 15;
    f32x4 accg[2][2] = {};
    f32x4 accu[2][2] = {};

    for (int kb = 0; kb < H_ / 32; ++kb) {
        __syncthreads();
        uint4 av = make_uint4(0u, 0u, 0u, 0u);
        if (atok >= 0)
            av = *(const uint4*)(tB + (size_t)atok * H_ + kb * 32 + ak);
        *(uint4*)&As[ar][ak] = av;
        {
            const float* src = wbase + (size_t)(kb * 32 + bk) * wrow;
            bf16x8 pg, pu;
            #pragma unroll
            for (int j = 0; j < 8; ++j) {
                pg[j] = (bf16)src[(size_t)j * wrow];
                pu[j] = (bf16)src[(size_t)j * wrow + IDIM];
            }
            *(bf16x8*)&Bg[bn][bk] = pg;
            *(bf16x8*)&Bu[bn][bk] = pu;
        }
        __syncthreads();
        bf16x8 a[2], bg[2], bu[2];
        a[0]  = *(const bf16x8*)&As[wm * 32 +      r][q * 8];
        a[1]  = *(const bf16x8*)&As[wm * 32 + 16 + r][q * 8];
        bg[0] = *(const bf16x8*)&Bg[wn * 32 +      r][q * 8];
        bg[1] = *(const bf16x8*)&Bg[wn * 32 + 16 + r][q * 8];
        bu[0] = *(const bf16x8*)&Bu[wn * 32 +      r][q * 8];
        bu[1] = *(const bf16x8*)&Bu[wn * 32 + 16 + r][q * 8];
        #pragma unroll
        for (int im = 0; im < 2; ++im)
            #pragma unroll
            for (int in = 0; in < 2; ++in) {
                accg[im][in] = __builtin_amdgcn_mfma_f32_16x16x32_bf16(a[im], bg[in], accg[im][in], 0, 0, 0);
                accu[im][in] = __builtin_amdgcn_mfma_f32_16x16x32_bf16(a[im], bu[in], accu[im][in], 0, 0, 0);
            }
    }

    const int sb = base[e];
    #pragma unroll
    for (int im = 0; im < 2; ++im)
        #pragma unroll
        for (int in = 0; in < 2; ++in)
            #pragma unroll
            for (int rg = 0; rg < 4; ++rg) {
                const int row = wm * 32 + im * 16 + q * 4 + rg;
                const int col = wn * 32 + in * 16 + r;
                if (m0 + row < ne) {
                    const float hg = accg[im][in][rg] + b13[e * 2 * IDIM + n0 + col];
                    const float hu = accu[im][in][rg] + b13[e * 2 * IDIM + IDIM + n0 + col];
                    const float gt = fminf(hg, LIMIT);
                    const float up = fminf(fmaxf(hu, -LIMIT), LIMIT);
                    const float av = (up + 1.0f) * gt / (1.0f + expf(-ALPHA * gt));
                    act[(size_t)(sb + m0 + row) * IDIM + n0 + col] = (bf16)av;
                }
            }
}

__global__ __launch_bounds__(256) void k_down(
    const bf16* __restrict__ act, const float* __restrict__ w2,
    const float* __restrict__ b2, const int* __restrict__ cnt,
    const int* __restrict__ base, const int* __restrict__ tok_list,
    const float* __restrict__ wgt_list, float* __restrict__ out)
{
    const int e  = blockIdx.z;
    const int ne = cnt[e];
    const int m0 = blockIdx.y * 64;
    if (m0 >= ne) return;
    const int n0  = blockIdx.x * 64;
    const int tid = threadIdx.x, lane = tid & 63, wave = tid >> 6;

    __shared__ __align__(16) bf16 As[64][40];
    __shared__ __align__(16) bf16 Bs[64][40];
    __shared__ int   stok[64];
    __shared__ float swgt[64];

    if (tid < 64) {
        const int s = m0 + tid;
        stok[tid] = (s < ne) ? tok_list[e * T_ + s] : -1;
        swgt[tid] = (s < ne) ? wgt_list[e * T_ + s] : 0.f;
    }
    __syncthreads();

    const int sb = base[e];
    const int ar = tid >> 2, ak = (tid & 3) * 8;
    const bool arow_ok = (m0 + ar) < ne;
    const int bn = tid & 63, bk = wave * 8;
    const float* wbase = w2 + (size_t)e * IDIM * H_ + n0 + bn;

    const int wm = wave >> 1, wn = wave & 1;
    const int q = lane >> 4, r = lane & 15;
    f32x4 acc[2][2] = {};

    for (int kb = 0; kb < IDIM / 32; ++kb) {
        __syncthreads();
        uint4 av = make_uint4(0u, 0u, 0u, 0u);
        if (arow_ok)
            av = *(const uint4*)(act + (size_t)(sb + m0 + ar) * IDIM + kb * 32 + ak);
        *(uint4*)&As[ar][ak] = av;
        {
            const float* src = wbase + (size_t)(kb * 32 + bk) * H_;
            bf16x8 pb;
            #pragma unroll
            for (int j = 0; j < 8; ++j) pb[j] = (bf16)src[(size_t)j * H_];
            *(bf16x8*)&Bs[bn][bk] = pb;
        }
        __syncthreads();
        bf16x8 a[2], b[2];
        a[0] = *(const bf16x8*)&As[wm * 32 +      r][q * 8];
        a[1] = *(const bf16x8*)&As[wm * 32 + 16 + r][q * 8];
        b[0] = *(const bf16x8*)&Bs[wn * 32 +      r][q * 8];
        b[1] = *(const bf16x8*)&Bs[wn * 32 + 16 + r][q * 8];
        #pragma unroll
        for (int im = 0; im < 2; ++im)
            #pragma unroll
            for (int in = 0; in < 2; ++in)
                acc[im][in] = __builtin_amdgcn_mfma_f32_16x16x32_bf16(a[im], b[in], acc[im][in], 0, 0, 0);
    }

    #pragma unroll
    for (int im = 0; im < 2; ++im)
        #pragma unroll
        for (int in = 0; in < 2; ++in)
            #pragma unroll
            for (int rg = 0; rg < 4; ++rg) {
                const int row = wm * 32 + im * 16 + q * 4 + rg;
                const int col = wn * 32 + in * 16 + r;
                if (m0 + row < ne) {
                    const int   tok = stok[row];
                    const float w   = swgt[row];
                    atomicAdd(&out[(size_t)tok * H_ + n0 + col], w * (acc[im][in][rg] + b2[e * H_ + n0 + col]));
                }
            }
}

// ---------------------------------------------------------------------------
extern "C" void kernel_launch(void* const* d_in, const int* in_sizes, int n_in,
                              void* d_out, int out_size, void* d_ws, size_t ws_size,
                              hipStream_t stream)
{
    const float* x        = (const float*)d_in[0];
    const float* norm_w   = (const float*)d_in[1];
    const float* router_w = (const float*)d_in[2];
    const float* router_b = (const float*)d_in[3];
    const float* w13      = (const float*)d_in[4];
    const float* b13      = (const float*)d_in[5];
    const float* w2       = (const float*)d_in[6];
    const float* b2       = (const float*)d_in[7];
    const float* manual_w = (const float*)d_in[8];
    const int*   layer_i  = (const int*)d_in[9];
    float* out = (float*)d_out;

    char* ws = (char*)d_ws;
    bf16*  tB   = (bf16*)ws;                              // 2 MB @ 0
    bf16*  act  = (bf16*)(ws + (2ull << 20));             // 8 MB @ 2M
    char*  meta = ws + (10ull << 20);
    int*   cnt      = (int*)meta;                         // 16 ints
    int*   basep    = (int*)(meta + 64);                  // 17 ints
    int*   tiln     = (int*)(meta + 256);                 // 1 int
    int*   tile_e   = (int*)(meta + 512);                 // 96 ints
    int*   tile_m0  = (int*)(meta + 1024);                // 96 ints
    int*   tok_list = (int*)(meta + (16ull << 10));       // 64 KB
    float* wgt_list = (float*)(meta + (16ull << 10) + (64ull << 10)); // 64 KB
    bf16*  w13p     = (bf16*)(ws + (12ull << 20));        // 64 MB
    bf16*  w2p      = (bf16*)(ws + (76ull << 20));        // 32 MB

    const bool fast = ws_size >= (108ull << 20);

    hipMemsetAsync(cnt, 0, E_ * sizeof(int), stream);

    k_rms_router<<<T_, 256, 0, stream>>>(x, norm_w, router_w, router_b,
                                         manual_w, layer_i, tB, out,
                                         cnt, tok_list, wgt_list);
    k_scan<<<1, 64, 0, stream>>>(cnt, basep, tiln, tile_e, tile_m0);

    if (fast) {
        dim3 gr13(2 * IDIM / 256, 32, E_);
        k_repack<<<gr13, 256, 0, stream>>>(w13, w13p, 2 * IDIM);
        dim3 gr2(H_ / 256, 32, E_);
        k_repack<<<gr2, 256, 0, stream>>>(w2, w2p, H_);

        dim3 gg(16, 80);
        k_gateup6<<<gg, 256, 0, stream>>>(tB, w13p, b13, cnt, basep, tiln,
                                          tile_e, tile_m0, tok_list, act);
        dim3 gd(8, 80);
        k_down6<<<gd, 256, 0, stream>>>(act, w2p, b2, cnt, basep, tiln,
                                        tile_e, tile_m0, tok_list, wgt_list, out);
    } else {
        dim3 gg(IDIM / 64, T_ / 64, E_);
        k_gateup<<<gg, 256, 0, stream>>>(tB, w13, b13, cnt, basep, tok_list, act);
        dim3 gd(H_ / 64, T_ / 64, E_);
        k_down<<<gd, 256, 0, stream>>>(act, w2, b2, cnt, basep, tok_list, wgt_list, out);
    }
}

// Round 4
// 401.694 us; speedup vs baseline: 1.1930x; 1.1804x over previous
//
#include <hip/hip_runtime.h>

#define T_    1024
#define H_    1024
#define IDIM  1024
#define E_    16
#define TOPK  4
#define ALPHA 1.702f
#define LIMIT 7.0f

typedef __bf16 bf16;
typedef __bf16 bf16x4 __attribute__((ext_vector_type(4)));
typedef __bf16 bf16x8 __attribute__((ext_vector_type(8)));
typedef float  f32x4  __attribute__((ext_vector_type(4)));

// Raw barrier WITHOUT vmcnt(0) drain: LDS ordering only. B-prefetch loads
// stay in flight across it; the compiler inserts counted vmcnt at the use.
#define BARRIER() do { \
    asm volatile("s_waitcnt lgkmcnt(0)" ::: "memory"); \
    __builtin_amdgcn_s_barrier(); } while (0)

// ---------------------------------------------------------------------------
// Kernel 1: RMSNorm + router logits + softmax/top-4 + routing lists.
// ---------------------------------------------------------------------------
__global__ __launch_bounds__(256) void k_rms_router(
    const float* __restrict__ x, const float* __restrict__ nw,
    const float* __restrict__ rw, const float* __restrict__ rb,
    const float* __restrict__ mw, const int* __restrict__ lidx,
    bf16* __restrict__ tB, float* __restrict__ out,
    int* __restrict__ cnt, int* __restrict__ tok_list,
    float* __restrict__ wgt_list)
{
    const int t = blockIdx.x, tid = threadIdx.x;
    const int lane = tid & 63, wave = tid >> 6;
    __shared__ float tbuf[H_];
    __shared__ float red[4];
    __shared__ float logits[E_];

    float4 xv = ((const float4*)(x + (size_t)t * H_))[tid];
    float4 wv = ((const float4*)nw)[tid];
    float ssq = xv.x*xv.x + xv.y*xv.y + xv.z*xv.z + xv.w*xv.w;
    #pragma unroll
    for (int off = 32; off; off >>= 1) ssq += __shfl_xor(ssq, off);
    if (lane == 0) red[wave] = ssq;
    __syncthreads();
    const float rms = rsqrtf((red[0] + red[1] + red[2] + red[3]) * (1.0f / H_) + 1e-5f);

    float4 tv;
    tv.x = xv.x * rms * wv.x;
    tv.y = xv.y * rms * wv.y;
    tv.z = xv.z * rms * wv.z;
    tv.w = xv.w * rms * wv.w;

    ((float4*)(out + (size_t)t * H_))[tid] = xv;      // residual init
    ((float4*)tbuf)[tid] = tv;
    bf16x4 tb = { (bf16)tv.x, (bf16)tv.y, (bf16)tv.z, (bf16)tv.w };
    *(bf16x4*)(tB + (size_t)t * H_ + tid * 4) = tb;
    __syncthreads();

    #pragma unroll
    for (int ei = 0; ei < 4; ++ei) {
        const int e = wave * 4 + ei;
        const float* wr = rw + (size_t)e * H_;
        float s = 0.f;
        #pragma unroll
        for (int j = 0; j < 16; ++j) {
            const int c = lane + j * 64;
            s += tbuf[c] * wr[c];
        }
        #pragma unroll
        for (int off = 32; off; off >>= 1) s += __shfl_xor(s, off);
        if (lane == 0) logits[e] = s + rb[e];
    }
    __syncthreads();

    if (tid == 0) {
        float g[E_];
        #pragma unroll
        for (int e = 0; e < E_; ++e) g[e] = logits[e];

        const int li = lidx[0];
        float ma = 0.f, lw[E_];
        #pragma unroll
        for (int e = 0; e < E_; ++e) { lw[e] = mw[li * E_ + e]; ma = fmaxf(ma, fabsf(lw[e])); }
        if (ma > 0.f) {
            float mx = -1e30f;
            for (int e = 0; e < E_; ++e) mx = fmaxf(mx, g[e]);
            float se = 0.f;
            for (int e = 0; e < E_; ++e) se += expf(g[e] - mx);
            const float lse = logf(se) + mx;
            float gl[E_], gmx = -1e30f, gmn = 1e30f;
            for (int e = 0; e < E_; ++e) { gl[e] = g[e] - lse; gmx = fmaxf(gmx, gl[e]); gmn = fminf(gmn, gl[e]); }
            for (int e = 0; e < E_; ++e) {
                if (lw[e] > 0.f)      gl[e] = gmx + 0.01f;
                else if (lw[e] < 0.f) gl[e] = gmn - 0.01f;
                g[e] = gl[e];
            }
        }

        float mx = -1e30f;
        #pragma unroll
        for (int e = 0; e < E_; ++e) mx = fmaxf(mx, g[e]);
        float p[E_];
        #pragma unroll
        for (int e = 0; e < E_; ++e) p[e] = expf(g[e] - mx);

        bool used[E_] = {};
        int   idx[TOPK];
        float twv[TOPK];
        float ssum = 0.f;
        for (int k = 0; k < TOPK; ++k) {
            int best = -1; float bv = -1e30f;
            for (int e = 0; e < E_; ++e)
                if (!used[e] && p[e] > bv) { bv = p[e]; best = e; }
            used[best] = true; idx[k] = best; twv[k] = bv; ssum += bv;
        }
        const float inv = 1.f / ssum;
        for (int k = 0; k < TOPK; ++k) {
            const int e = idx[k];
            const int slot = atomicAdd(&cnt[e], 1);
            tok_list[e * T_ + slot] = t;
            wgt_list[e * T_ + slot] = twv[k] * inv;
        }
    }
}

// ---------------------------------------------------------------------------
// Kernel 2: scan + tile table (wave-parallel).
// ---------------------------------------------------------------------------
__global__ void k_scan(const int* __restrict__ cnt, int* __restrict__ base,
                       int* __restrict__ tiln, int* __restrict__ tile_e,
                       int* __restrict__ tile_m0)
{
    const int lane = threadIdx.x;            // 64 threads, lanes 0..15 active
    int c = (lane < E_) ? cnt[lane] : 0;

    int s = c;
    #pragma unroll
    for (int off = 1; off < 16; off <<= 1) {
        int tv = __shfl_up(s, off);
        if ((lane & 15) >= off) s += tv;
    }
    if (lane < E_) base[lane] = s - c;
    if (lane == E_ - 1) base[E_] = s;

    int nt = (lane < E_) ? ((c + 63) >> 6) : 0;
    int ts = nt;
    #pragma unroll
    for (int off = 1; off < 16; off <<= 1) {
        int tv = __shfl_up(ts, off);
        if ((lane & 15) >= off) ts += tv;
    }
    if (lane == E_ - 1) tiln[0] = ts;
    if (lane < E_) {
        const int t0 = ts - nt;
        for (int i = 0; i < nt; ++i) {
            if (t0 + i < 96) { tile_e[t0 + i] = lane; tile_m0[t0 + i] = i * 64; }
        }
    }
}

// ---------------------------------------------------------------------------
// Repack: W [E][1024(k)][Ndim(n)] fp32 -> bf16 MFMA-fragment tiles.
// out[((e*(Ndim/16) + nb)*32 + kb)*512 + l*8 + j] = W[e][kb*32+(l>>4)*8+j][nb*16+(l&15)]
// ---------------------------------------------------------------------------
__global__ __launch_bounds__(256) void k_repack(
    const float* __restrict__ W, bf16* __restrict__ out, int Ndim)
{
    __shared__ float tile[32][260];
    const int e = blockIdx.z, kb = blockIdx.y, n0 = blockIdx.x * 256;
    const int t = threadIdx.x;
    const int nbs = Ndim >> 4;

    const float* src = W + ((size_t)e * 1024 + (size_t)kb * 32) * Ndim + n0;
    #pragma unroll
    for (int i = 0; i < 8; ++i) {
        const int idx = i * 256 + t;
        const int k = idx >> 6, c4 = (idx & 63) * 4;
        float4 v = *(const float4*)(src + (size_t)k * Ndim + c4);
        *(float4*)&tile[k][c4] = v;
    }
    __syncthreads();

    const int f = t >> 4;
    const int lg = (t & 15) * 4;
    bf16* dst = out + (((size_t)(e * nbs + n0 / 16 + f)) * 32 + kb) * 512;
    #pragma unroll
    for (int li = 0; li < 4; ++li) {
        const int l = lg + li, q = l >> 4, r = l & 15;
        bf16x8 p;
        #pragma unroll
        for (int j = 0; j < 8; ++j) p[j] = (bf16)tile[q * 8 + j][f * 16 + r];
        *(bf16x8*)(dst + l * 8) = p;
    }
}

// ---------------------------------------------------------------------------
// Kernel 3: grouped gate_up GEMM. Round-0 structure (LDS A in fragment
// order shared by 4 waves, register-direct packed B) with the barrier
// schedule repaired: raw s_barrier + lgkmcnt-only (NO vmcnt(0) drain),
// B prefetched distance-2 and issued AFTER the MFMA cluster, so the
// compiler emits counted vmcnt at the use — loads stay in flight across
// barriers. BM=64, BK=64, 16 k-steps. grid: (16, 80); wave w handles
// gate nb = bx*4+w and up nb = gate+64.
// ---------------------------------------------------------------------------
__global__ __launch_bounds__(256) void k_gateup3(
    const bf16* __restrict__ tB, const bf16* __restrict__ w13p,
    const float* __restrict__ b13, const int* __restrict__ cnt,
    const int* __restrict__ base, const int* __restrict__ tiln,
    const int* __restrict__ tile_e, const int* __restrict__ tile_m0,
    const int* __restrict__ tok_list, bf16* __restrict__ act)
{
    const int ti = blockIdx.y;
    if (ti >= tiln[0]) return;
    const int e  = tile_e[ti];
    const int m0 = tile_m0[ti];
    const int ne = cnt[e];

    const int tid = threadIdx.x, lane = tid & 63, wave = tid >> 6;
    const int q = lane >> 4, r = lane & 15;

    // A tile in LDS, fragment order: frag (mf,kc) at [(mf*2+kc)*64 + lane]*8
    __shared__ __align__(16) bf16 As[8 * 64 * 8];

    // --- staging coords: thread t -> row m = t>>2, 32B chunk kq = t&3 ---
    const int m   = tid >> 2, kq = tid & 3;
    const int mf_s = m >> 4, r_s = m & 15;
    const int kc_s = kq >> 1, q_s = (kq & 1) * 2;
    bf16* wr0 = As + ((size_t)((mf_s * 2 + kc_s) * 64 + q_s * 16 + r_s)) * 8;
    bf16* wr1 = wr0 + 16 * 8;
    int srow = m0 + m; srow = srow < ne ? srow : ne - 1;
    const bf16* pA = tB + (size_t)tok_list[e * T_ + srow] * H_ + kq * 16;

    const int nb_g = blockIdx.x * 4 + wave;
    const bf16* pBg0 = w13p + ((size_t)(e * 128 + nb_g     ) * 32) * 512 + lane * 8;
    const bf16* pBu0 = w13p + ((size_t)(e * 128 + nb_g + 64) * 32) * 512 + lane * 8;

    f32x4 accg[4] = {};
    f32x4 accu[4] = {};
    uint4 ar0a, ar0b, ar1a, ar1b;
    bf16x8 bg0[2], bu0[2], bg1[2], bu1[2];

#define LOADA(A0, A1) do { \
    A0 = *(const uint4*)pA; A1 = *(const uint4*)(pA + 8); pA += 64; } while (0)
#define STAGEA(A0, A1) do { \
    *(uint4*)wr0 = A0; *(uint4*)wr1 = A1; } while (0)
#define LOADB(BG, BU, s) do { \
    const int ss_ = (s) < 16 ? (s) : 15; \
    BG[0] = *(const bf16x8*)(pBg0 + (size_t)ss_ * 1024); \
    BG[1] = *(const bf16x8*)(pBg0 + (size_t)ss_ * 1024 + 512); \
    BU[0] = *(const bf16x8*)(pBu0 + (size_t)ss_ * 1024); \
    BU[1] = *(const bf16x8*)(pBu0 + (size_t)ss_ * 1024 + 512); } while (0)
#define COMPUTE(BG, BU) do { \
    _Pragma("unroll") \
    for (int kc = 0; kc < 2; ++kc) { \
        bf16x8 afr[4]; \
        _Pragma("unroll") \
        for (int mf = 0; mf < 4; ++mf) \
            afr[mf] = *(const bf16x8*)(As + ((size_t)((mf * 2 + kc) * 64 + lane)) * 8); \
        _Pragma("unroll") \
        for (int mf = 0; mf < 4; ++mf) { \
            accg[mf] = __builtin_amdgcn_mfma_f32_16x16x32_bf16(afr[mf], BG[kc], accg[mf], 0, 0, 0); \
            accu[mf] = __builtin_amdgcn_mfma_f32_16x16x32_bf16(afr[mf], BU[kc], accu[mf], 0, 0, 0); \
        } \
    } } while (0)

    LOADA(ar0a, ar0b);
    LOADB(bg0, bu0, 0);
    LOADB(bg1, bu1, 1);
    #pragma unroll 1
    for (int kb = 0; kb < 16; kb += 2) {
        BARRIER();                       // As free to overwrite (lgkm only)
        STAGEA(ar0a, ar0b);
        LOADA(ar1a, ar1b);               // A for step kb+1 (junk on last, unused)
        BARRIER();                       // As ready; B loads still in flight
        COMPUTE(bg0, bu0);               // counted vmcnt before first B use
        LOADB(bg0, bu0, kb + 2);         // distance-2 prefetch (clamped)

        BARRIER();
        STAGEA(ar1a, ar1b);
        LOADA(ar0a, ar0b);
        BARRIER();
        COMPUTE(bg1, bu1);
        LOADB(bg1, bu1, kb + 3);
    }
#undef LOADA
#undef STAGEA
#undef LOADB
#undef COMPUTE

    // --- epilogue ---
    const int sb = base[e];
    const int cg = nb_g * 16 + r;                 // column in [0, IDIM)
    const float bgv = b13[e * 2 * IDIM + cg];
    const float buv = b13[e * 2 * IDIM + IDIM + cg];
    #pragma unroll
    for (int mf = 0; mf < 4; ++mf) {
        #pragma unroll
        for (int rg = 0; rg < 4; ++rg) {
            const int row = mf * 16 + q * 4 + rg;
            if (m0 + row < ne) {
                const float hg = accg[mf][rg] + bgv;
                const float hu = accu[mf][rg] + buv;
                const float gt = fminf(hg, LIMIT);
                const float up = fminf(fmaxf(hu, -LIMIT), LIMIT);
                const float av = (up + 1.0f) * gt / (1.0f + expf(-ALPHA * gt));
                act[(size_t)(sb + m0 + row) * IDIM + cg] = (bf16)av;
            }
        }
    }
}

// ---------------------------------------------------------------------------
// Kernel 4: grouped down GEMM + weighted atomic combine. Same repaired
// schedule. grid: (8, 80); wave w handles nb = bx*8 + w*2 + {0,1}.
// ---------------------------------------------------------------------------
__global__ __launch_bounds__(256) void k_down3(
    const bf16* __restrict__ act, const bf16* __restrict__ w2p,
    const float* __restrict__ b2, const int* __restrict__ cnt,
    const int* __restrict__ base, const int* __restrict__ tiln,
    const int* __restrict__ tile_e, const int* __restrict__ tile_m0,
    const int* __restrict__ tok_list, const float* __restrict__ wgt_list,
    float* __restrict__ out)
{
    const int ti = blockIdx.y;
    if (ti >= tiln[0]) return;
    const int e  = tile_e[ti];
    const int m0 = tile_m0[ti];
    const int ne = cnt[e];
    const int sb = base[e];

    const int tid = threadIdx.x, lane = tid & 63, wave = tid >> 6;
    const int q = lane >> 4, r = lane & 15;

    __shared__ __align__(16) bf16 As[8 * 64 * 8];

    const int m   = tid >> 2, kq = tid & 3;
    const int mf_s = m >> 4, r_s = m & 15;
    const int kc_s = kq >> 1, q_s = (kq & 1) * 2;
    bf16* wr0 = As + ((size_t)((mf_s * 2 + kc_s) * 64 + q_s * 16 + r_s)) * 8;
    bf16* wr1 = wr0 + 16 * 8;
    int srow = m0 + m; srow = srow < ne ? srow : ne - 1;
    const bf16* pA = act + (size_t)(sb + srow) * IDIM + kq * 16;

    const int nb0 = blockIdx.x * 8 + wave * 2;
    const bf16* pB0b = w2p + ((size_t)(e * 64 + nb0    ) * 32) * 512 + lane * 8;
    const bf16* pB1b = w2p + ((size_t)(e * 64 + nb0 + 1) * 32) * 512 + lane * 8;

    f32x4 acc[4][2] = {};
    uint4 ar0a, ar0b, ar1a, ar1b;
    bf16x8 bA0[2], bB0[2], bA1[2], bB1[2];

#define LOADA(A0, A1) do { \
    A0 = *(const uint4*)pA; A1 = *(const uint4*)(pA + 8); pA += 64; } while (0)
#define STAGEA(A0, A1) do { \
    *(uint4*)wr0 = A0; *(uint4*)wr1 = A1; } while (0)
#define LOADB(B0, B1, s) do { \
    const int ss_ = (s) < 16 ? (s) : 15; \
    B0[0] = *(const bf16x8*)(pB0b + (size_t)ss_ * 1024); \
    B0[1] = *(const bf16x8*)(pB0b + (size_t)ss_ * 1024 + 512); \
    B1[0] = *(const bf16x8*)(pB1b + (size_t)ss_ * 1024); \
    B1[1] = *(const bf16x8*)(pB1b + (size_t)ss_ * 1024 + 512); } while (0)
#define COMPUTE(B0, B1) do { \
    _Pragma("unroll") \
    for (int kc = 0; kc < 2; ++kc) { \
        bf16x8 afr[4]; \
        _Pragma("unroll") \
        for (int mf = 0; mf < 4; ++mf) \
            afr[mf] = *(const bf16x8*)(As + ((size_t)((mf * 2 + kc) * 64 + lane)) * 8); \
        _Pragma("unroll") \
        for (int mf = 0; mf < 4; ++mf) { \
            acc[mf][0] = __builtin_amdgcn_mfma_f32_16x16x32_bf16(afr[mf], B0[kc], acc[mf][0], 0, 0, 0); \
            acc[mf][1] = __builtin_amdgcn_mfma_f32_16x16x32_bf16(afr[mf], B1[kc], acc[mf][1], 0, 0, 0); \
        } \
    } } while (0)

    LOADA(ar0a, ar0b);
    LOADB(bA0, bB0, 0);
    LOADB(bA1, bB1, 1);
    #pragma unroll 1
    for (int kb = 0; kb < 16; kb += 2) {
        BARRIER();
        STAGEA(ar0a, ar0b);
        LOADA(ar1a, ar1b);
        BARRIER();
        COMPUTE(bA0, bB0);
        LOADB(bA0, bB0, kb + 2);

        BARRIER();
        STAGEA(ar1a, ar1b);
        LOADA(ar0a, ar0b);
        BARRIER();
        COMPUTE(bA1, bB1);
        LOADB(bA1, bB1, kb + 3);
    }
#undef LOADA
#undef STAGEA
#undef LOADB
#undef COMPUTE

    #pragma unroll
    for (int nf = 0; nf < 2; ++nf) {
        const int ch = (nb0 + nf) * 16 + r;
        const float bb = b2[e * H_ + ch];
        #pragma unroll
        for (int mf = 0; mf < 4; ++mf) {
            #pragma unroll
            for (int rg = 0; rg < 4; ++rg) {
                const int row = mf * 16 + q * 4 + rg;
                const int s = m0 + row;
                if (s < ne) {
                    const int   tok = tok_list[e * T_ + s];
                    const float w   = wgt_list[e * T_ + s];
                    atomicAdd(&out[(size_t)tok * H_ + ch], w * (acc[mf][nf][rg] + bb));
                }
            }
        }
    }
}

// ---------------------------------------------------------------------------
// Fallback (round-1) GEMMs, used if ws too small for packed weights.
// ---------------------------------------------------------------------------
__global__ __launch_bounds__(256) void k_gateup(
    const bf16* __restrict__ tB, const float* __restrict__ w13,
    const float* __restrict__ b13, const int* __restrict__ cnt,
    const int* __restrict__ base, const int* __restrict__ tok_list,
    bf16* __restrict__ act)
{
    const int e  = blockIdx.z;
    const int ne = cnt[e];
    const int m0 = blockIdx.y * 64;
    if (m0 >= ne) return;
    const int n0  = blockIdx.x * 64;
    const int tid = threadIdx.x, lane = tid & 63, wave = tid >> 6;

    __shared__ __align__(16) bf16 As[64][40];
    __shared__ __align__(16) bf16 Bg[64][40];
    __shared__ __align__(16) bf16 Bu[64][40];
    __shared__ int stok[64];

    if (tid < 64) {
        const int s = m0 + tid;
        stok[tid] = (s < ne) ? tok_list[e * T_ + s] : -1;
    }
    __syncthreads();

    const int ar = tid >> 2, ak = (tid & 3) * 8;
    const int atok = stok[ar];
    const int bn = tid & 63, bk = wave * 8;
    const size_t wrow = (size_t)(2 * IDIM);
    const float* wbase = w13 + (size_t)e * H_ * wrow + n0 + bn;

    const int wm = wave >> 1, wn = wave & 1;
    const int q = lane >> 4, r = lane & 15;
    f32x4 accg[2][2] = {};
    f32x4 accu[2][2] = {};

    for (int kb = 0; kb < H_ / 32; ++kb) {
        __syncthreads();
        uint4 av = make_uint4(0u, 0u, 0u, 0u);
        if (atok >= 0)
            av = *(const uint4*)(tB + (size_t)atok * H_ + kb * 32 + ak);
        *(uint4*)&As[ar][ak] = av;
        {
            const float* src = wbase + (size_t)(kb * 32 + bk) * wrow;
            bf16x8 pg, pu;
            #pragma unroll
            for (int j = 0; j < 8; ++j) {
                pg[j] = (bf16)src[(size_t)j * wrow];
                pu[j] = (bf16)src[(size_t)j * wrow + IDIM];
            }
            *(bf16x8*)&Bg[bn][bk] = pg;
            *(bf16x8*)&Bu[bn][bk] = pu;
        }
        __syncthreads();
        bf16x8 a[2], bg[2], bu[2];
        a[0]  = *(const bf16x8*)&As[wm * 32 +      r][q * 8];
        a[1]  = *(const bf16x8*)&As[wm * 32 + 16 + r][q * 8];
        bg[0] = *(const bf16x8*)&Bg[wn * 32 +      r][q * 8];
        bg[1] = *(const bf16x8*)&Bg[wn * 32 + 16 + r][q * 8];
        bu[0] = *(const bf16x8*)&Bu[wn * 32 +      r][q * 8];
        bu[1] = *(const bf16x8*)&Bu[wn * 32 + 16 + r][q * 8];
        #pragma unroll
        for (int im = 0; im < 2; ++im)
            #pragma unroll
            for (int in = 0; in < 2; ++in) {
                accg[im][in] = __builtin_amdgcn_mfma_f32_16x16x32_bf16(a[im], bg[in], accg[im][in], 0, 0, 0);
                accu[im][in] = __builtin_amdgcn_mfma_f32_16x16x32_bf16(a[im], bu[in], accu[im][in], 0, 0, 0);
            }
    }

    const int sb = base[e];
    #pragma unroll
    for (int im = 0; im < 2; ++im)
        #pragma unroll
        for (int in = 0; in < 2; ++in)
            #pragma unroll
            for (int rg = 0; rg < 4; ++rg) {
                const int row = wm * 32 + im * 16 + q * 4 + rg;
                const int col = wn * 32 + in * 16 + r;
                if (m0 + row < ne) {
                    const float hg = accg[im][in][rg] + b13[e * 2 * IDIM + n0 + col];
                    const float hu = accu[im][in][rg] + b13[e * 2 * IDIM + IDIM + n0 + col];
                    const float gt = fminf(hg, LIMIT);
                    const float up = fminf(fmaxf(hu, -LIMIT), LIMIT);
                    const float av = (up + 1.0f) * gt / (1.0f + expf(-ALPHA * gt));
                    act[(size_t)(sb + m0 + row) * IDIM + n0 + col] = (bf16)av;
                }
            }
}

__global__ __launch_bounds__(256) void k_down(
    const bf16* __restrict__ act, const float* __restrict__ w2,
    const float* __restrict__ b2, const int* __restrict__ cnt,
    const int* __restrict__ base, const int* __restrict__ tok_list,
    const float* __restrict__ wgt_list, float* __restrict__ out)
{
    const int e  = blockIdx.z;
    const int ne = cnt[e];
    const int m0 = blockIdx.y * 64;
    if (m0 >= ne) return;
    const int n0  = blockIdx.x * 64;
    const int tid = threadIdx.x, lane = tid & 63, wave = tid >> 6;

    __shared__ __align__(16) bf16 As[64][40];
    __shared__ __align__(16) bf16 Bs[64][40];
    __shared__ int   stok[64];
    __shared__ float swgt[64];

    if (tid < 64) {
        const int s = m0 + tid;
        stok[tid] = (s < ne) ? tok_list[e * T_ + s] : -1;
        swgt[tid] = (s < ne) ? wgt_list[e * T_ + s] : 0.f;
    }
    __syncthreads();

    const int sb = base[e];
    const int ar = tid >> 2, ak = (tid & 3) * 8;
    const bool arow_ok = (m0 + ar) < ne;
    const int bn = tid & 63, bk = wave * 8;
    const float* wbase = w2 + (size_t)e * IDIM * H_ + n0 + bn;

    const int wm = wave >> 1, wn = wave & 1;
    const int q = lane >> 4, r = lane & 15;
    f32x4 acc[2][2] = {};

    for (int kb = 0; kb < IDIM / 32; ++kb) {
        __syncthreads();
        uint4 av = make_uint4(0u, 0u, 0u, 0u);
        if (arow_ok)
            av = *(const uint4*)(act + (size_t)(sb + m0 + ar) * IDIM + kb * 32 + ak);
        *(uint4*)&As[ar][ak] = av;
        {
            const float* src = wbase + (size_t)(kb * 32 + bk) * H_;
            bf16x8 pb;
            #pragma unroll
            for (int j = 0; j < 8; ++j) pb[j] = (bf16)src[(size_t)j * H_];
            *(bf16x8*)&Bs[bn][bk] = pb;
        }
        __syncthreads();
        bf16x8 a[2], b[2];
        a[0] = *(const bf16x8*)&As[wm * 32 +      r][q * 8];
        a[1] = *(const bf16x8*)&As[wm * 32 + 16 + r][q * 8];
        b[0] = *(const bf16x8*)&Bs[wn * 32 +      r][q * 8];
        b[1] = *(const bf16x8*)&Bs[wn * 32 + 16 + r][q * 8];
        #pragma unroll
        for (int im = 0; im < 2; ++im)
            #pragma unroll
            for (int in = 0; in < 2; ++in)
                acc[im][in] = __builtin_amdgcn_mfma_f32_16x16x32_bf16(a[im], b[in], acc[im][in], 0, 0, 0);
    }

    #pragma unroll
    for (int im = 0; im < 2; ++im)
        #pragma unroll
        for (int in = 0; in < 2; ++in)
            #pragma unroll
            for (int rg = 0; rg < 4; ++rg) {
                const int row = wm * 32 + im * 16 + q * 4 + rg;
                const int col = wn * 32 + in * 16 + r;
                if (m0 + row < ne) {
                    const int   tok = stok[row];
                    const float w   = swgt[row];
                    atomicAdd(&out[(size_t)tok * H_ + n0 + col], w * (acc[im][in][rg] + b2[e * H_ + n0 + col]));
                }
            }
}

// ---------------------------------------------------------------------------
extern "C" void kernel_launch(void* const* d_in, const int* in_sizes, int n_in,
                              void* d_out, int out_size, void* d_ws, size_t ws_size,
                              hipStream_t stream)
{
    const float* x        = (const float*)d_in[0];
    const float* norm_w   = (const float*)d_in[1];
    const float* router_w = (const float*)d_in[2];
    const float* router_b = (const float*)d_in[3];
    const float* w13      = (const float*)d_in[4];
    const float* b13      = (const float*)d_in[5];
    const float* w2       = (const float*)d_in[6];
    const float* b2       = (const float*)d_in[7];
    const float* manual_w = (const float*)d_in[8];
    const int*   layer_i  = (const int*)d_in[9];
    float* out = (float*)d_out;

    char* ws = (char*)d_ws;
    bf16*  tB   = (bf16*)ws;                              // 2 MB @ 0
    bf16*  act  = (bf16*)(ws + (2ull << 20));             // 8 MB @ 2M
    char*  meta = ws + (10ull << 20);
    int*   cnt      = (int*)meta;                         // 16 ints
    int*   basep    = (int*)(meta + 64);                  // 17 ints
    int*   tiln     = (int*)(meta + 256);                 // 1 int
    int*   tile_e   = (int*)(meta + 512);                 // 96 ints
    int*   tile_m0  = (int*)(meta + 1024);                // 96 ints
    int*   tok_list = (int*)(meta + (16ull << 10));       // 64 KB
    float* wgt_list = (float*)(meta + (16ull << 10) + (64ull << 10)); // 64 KB
    bf16*  w13p     = (bf16*)(ws + (12ull << 20));        // 64 MB
    bf16*  w2p      = (bf16*)(ws + (76ull << 20));        // 32 MB

    const bool fast = ws_size >= (108ull << 20);

    hipMemsetAsync(cnt, 0, E_ * sizeof(int), stream);

    k_rms_router<<<T_, 256, 0, stream>>>(x, norm_w, router_w, router_b,
                                         manual_w, layer_i, tB, out,
                                         cnt, tok_list, wgt_list);
    k_scan<<<1, 64, 0, stream>>>(cnt, basep, tiln, tile_e, tile_m0);

    if (fast) {
        dim3 gr13(2 * IDIM / 256, 32, E_);
        k_repack<<<gr13, 256, 0, stream>>>(w13, w13p, 2 * IDIM);
        dim3 gr2(H_ / 256, 32, E_);
        k_repack<<<gr2, 256, 0, stream>>>(w2, w2p, H_);

        dim3 gg(16, 80);
        k_gateup3<<<gg, 256, 0, stream>>>(tB, w13p, b13, cnt, basep, tiln,
                                          tile_e, tile_m0, tok_list, act);
        dim3 gd(8, 80);
        k_down3<<<gd, 256, 0, stream>>>(act, w2p, b2, cnt, basep, tiln,
                                        tile_e, tile_m0, tok_list, wgt_list, out);
    } else {
        dim3 gg(IDIM / 64, T_ / 64, E_);
        k_gateup<<<gg, 256, 0, stream>>>(tB, w13, b13, cnt, basep, tok_list, act);
        dim3 gd(H_ / 64, T_ / 64, E_);
        k_down<<<gd, 256, 0, stream>>>(act, w2, b2, cnt, basep, tok_list, wgt_list, out);
    }
}

// Round 7
// 373.240 us; speedup vs baseline: 1.2840x; 1.0762x over previous
//
#include <hip/hip_runtime.h>

#define T_    1024
#define H_    1024
#define IDIM  1024
#define E_    16
#define TOPK  4
#define ALPHA 1.702f
#define LIMIT 7.0f

typedef __bf16 bf16;
typedef __bf16 bf16x4 __attribute__((ext_vector_type(4)));
typedef __bf16 bf16x8 __attribute__((ext_vector_type(8)));
typedef float  f32x4  __attribute__((ext_vector_type(4)));

// Raw barrier WITHOUT vmcnt(0) drain: LDS ordering only (proven in the
// passing round-4 kernel). Global prefetch loads stay in flight across it.
#define BARRIER() do { \
    asm volatile("s_waitcnt lgkmcnt(0)" ::: "memory"); \
    __builtin_amdgcn_s_barrier(); } while (0)

// ---------------------------------------------------------------------------
// Kernel 1: RMSNorm + router logits + softmax/top-4 + routing lists.
// ---------------------------------------------------------------------------
__global__ __launch_bounds__(256) void k_rms_router(
    const float* __restrict__ x, const float* __restrict__ nw,
    const float* __restrict__ rw, const float* __restrict__ rb,
    const float* __restrict__ mw, const int* __restrict__ lidx,
    bf16* __restrict__ tB, float* __restrict__ out,
    int* __restrict__ cnt, int* __restrict__ tok_list,
    float* __restrict__ wgt_list)
{
    const int t = blockIdx.x, tid = threadIdx.x;
    const int lane = tid & 63, wave = tid >> 6;
    __shared__ float tbuf[H_];
    __shared__ float red[4];
    __shared__ float logits[E_];

    float4 xv = ((const float4*)(x + (size_t)t * H_))[tid];
    float4 wv = ((const float4*)nw)[tid];
    float ssq = xv.x*xv.x + xv.y*xv.y + xv.z*xv.z + xv.w*xv.w;
    #pragma unroll
    for (int off = 32; off; off >>= 1) ssq += __shfl_xor(ssq, off);
    if (lane == 0) red[wave] = ssq;
    __syncthreads();
    const float rms = rsqrtf((red[0] + red[1] + red[2] + red[3]) * (1.0f / H_) + 1e-5f);

    float4 tv;
    tv.x = xv.x * rms * wv.x;
    tv.y = xv.y * rms * wv.y;
    tv.z = xv.z * rms * wv.z;
    tv.w = xv.w * rms * wv.w;

    ((float4*)(out + (size_t)t * H_))[tid] = xv;      // residual init
    ((float4*)tbuf)[tid] = tv;
    bf16x4 tb = { (bf16)tv.x, (bf16)tv.y, (bf16)tv.z, (bf16)tv.w };
    *(bf16x4*)(tB + (size_t)t * H_ + tid * 4) = tb;
    __syncthreads();

    #pragma unroll
    for (int ei = 0; ei < 4; ++ei) {
        const int e = wave * 4 + ei;
        const float* wr = rw + (size_t)e * H_;
        float s = 0.f;
        #pragma unroll
        for (int j = 0; j < 16; ++j) {
            const int c = lane + j * 64;
            s += tbuf[c] * wr[c];
        }
        #pragma unroll
        for (int off = 32; off; off >>= 1) s += __shfl_xor(s, off);
        if (lane == 0) logits[e] = s + rb[e];
    }
    __syncthreads();

    if (tid == 0) {
        float g[E_];
        #pragma unroll
        for (int e = 0; e < E_; ++e) g[e] = logits[e];

        const int li = lidx[0];
        float ma = 0.f, lw[E_];
        #pragma unroll
        for (int e = 0; e < E_; ++e) { lw[e] = mw[li * E_ + e]; ma = fmaxf(ma, fabsf(lw[e])); }
        if (ma > 0.f) {
            float mx = -1e30f;
            for (int e = 0; e < E_; ++e) mx = fmaxf(mx, g[e]);
            float se = 0.f;
            for (int e = 0; e < E_; ++e) se += expf(g[e] - mx);
            const float lse = logf(se) + mx;
            float gl[E_], gmx = -1e30f, gmn = 1e30f;
            for (int e = 0; e < E_; ++e) { gl[e] = g[e] - lse; gmx = fmaxf(gmx, gl[e]); gmn = fminf(gmn, gl[e]); }
            for (int e = 0; e < E_; ++e) {
                if (lw[e] > 0.f)      gl[e] = gmx + 0.01f;
                else if (lw[e] < 0.f) gl[e] = gmn - 0.01f;
                g[e] = gl[e];
            }
        }

        float mx = -1e30f;
        #pragma unroll
        for (int e = 0; e < E_; ++e) mx = fmaxf(mx, g[e]);
        float p[E_];
        #pragma unroll
        for (int e = 0; e < E_; ++e) p[e] = expf(g[e] - mx);

        bool used[E_] = {};
        int   idx[TOPK];
        float twv[TOPK];
        float ssum = 0.f;
        for (int k = 0; k < TOPK; ++k) {
            int best = -1; float bv = -1e30f;
            for (int e = 0; e < E_; ++e)
                if (!used[e] && p[e] > bv) { bv = p[e]; best = e; }
            used[best] = true; idx[k] = best; twv[k] = bv; ssum += bv;
        }
        const float inv = 1.f / ssum;
        for (int k = 0; k < TOPK; ++k) {
            const int e = idx[k];
            const int slot = atomicAdd(&cnt[e], 1);
            tok_list[e * T_ + slot] = t;
            wgt_list[e * T_ + slot] = twv[k] * inv;
        }
    }
}

// ---------------------------------------------------------------------------
// Inline routing scan — single-thread, trivially-simple version (16
// independent L2 loads + serial loop). Writes {tiln, e, m0, ne, sb}.
// ---------------------------------------------------------------------------
__device__ __forceinline__ void inline_scan(const int* __restrict__ cnt,
                                            int ti, int tid, int* sm)
{
    if (tid == 0) {
        int c0[E_];
        #pragma unroll
        for (int e = 0; e < E_; ++e) c0[e] = cnt[e];   // independent loads
        int s = 0, nt = 0, ee = 0, mm0 = 0, nee = 0, sbb = 0;
        #pragma unroll
        for (int e = 0; e < E_; ++e) {
            const int c = c0[e];
            const int tcnt = (c + 63) >> 6;
            if (ti >= nt && ti < nt + tcnt) {
                ee = e; mm0 = (ti - nt) * 64; nee = c; sbb = s;
            }
            s += c; nt += tcnt;
        }
        sm[0] = nt; sm[1] = ee; sm[2] = mm0; sm[3] = nee; sm[4] = sbb;
    }
    __syncthreads();
}

// ---------------------------------------------------------------------------
// Kernel 2: grouped gate_up GEMM, fp32 weights consumed DIRECTLY (no repack
// pass): per k-step each thread loads 8 x float4 column-vectors of W13
// (coalesced along n), converts to bf16, writes fragment-ordered LDS with a
// +RB>>1 skew. A staged in LDS in fragment order (round-0-proven scheme).
// 2-barrier loop identical to the round-4 passing kernel. BM=64, BK=64.
// grid: (16, 80); wave w: gate nb = bx*4+w, up nb = gate+64.
// ---------------------------------------------------------------------------
__global__ __launch_bounds__(256) void k_gateup7(
    const bf16* __restrict__ tB, const float* __restrict__ w13,
    const float* __restrict__ b13, const int* __restrict__ cnt,
    const int* __restrict__ tok_list, bf16* __restrict__ act)
{
    const int ti = blockIdx.y, bx = blockIdx.x;
    const int tid = threadIdx.x, lane = tid & 63, wave = tid >> 6;
    const int q = lane >> 4, r = lane & 15;

    __shared__ __align__(16) bf16 As[8 * 64 * 8];          // 8 KB
    __shared__ __align__(16) bf16 Bs[1032 * 8];            // 16.5 KB (skewed)
    __shared__ int sm[5];

    inline_scan(cnt, ti, tid, sm);
    if (ti >= sm[0]) return;
    const int e = sm[1], m0 = sm[2], ne = sm[3], sb = sm[4];

    // --- A staging coords (proven round-0 scheme) ---
    const int m   = tid >> 2, kq = tid & 3;
    const int mf_s = m >> 4, r_s = m & 15;
    const int kc_s = kq >> 1, q_s = (kq & 1) * 2;
    bf16* wr0 = As + ((size_t)((mf_s * 2 + kc_s) * 64 + q_s * 16 + r_s)) * 8;
    bf16* wr1 = wr0 + 16 * 8;
    int srow = m0 + m; srow = srow < ne ? srow : ne - 1;
    const bf16* pA = tB + (size_t)tok_list[e * T_ + srow] * H_ + kq * 16;

    // --- B staging coords: thread (c4 = tid&31, q6 = tid>>5) ---
    const int c4 = tid & 31, q6 = tid >> 5;
    const int kcs = q6 >> 2, qs = q6 & 3;
    const int cc = c4 * 4;                       // 0..124 (gate | up halves)
    const int fB = c4 >> 2, r0 = (c4 & 3) * 4;
    const int RB = fB * 2 + kcs;
    bf16* bwr = Bs + ((size_t)(RB * 64 + (RB >> 1) + qs * 16 + r0)) * 8;
    const int col = (cc < 64) ? (bx * 64 + cc) : (IDIM + bx * 64 + (cc - 64));
    const float* pB = w13 + (size_t)e * H_ * (2 * IDIM)
                          + (size_t)(kcs * 32 + qs * 8) * (2 * IDIM) + col;

    f32x4 accg[4] = {};
    f32x4 accu[4] = {};
    uint4  a0a, a0b, a1a, a1b;
    f32x4  br0[8], br1[8];

#define LOADA(A0, A1, s) do { const int ss_ = (s) < 16 ? (s) : 15; \
    A0 = *(const uint4*)(pA + ss_ * 64); \
    A1 = *(const uint4*)(pA + ss_ * 64 + 8); } while (0)
#define LOADB(BR, s) do { const int ss_ = (s) < 16 ? (s) : 15; \
    _Pragma("unroll") \
    for (int j = 0; j < 8; ++j) \
        BR[j] = *(const f32x4*)(pB + (size_t)(ss_ * 64 + j) * (2 * IDIM)); } while (0)
#define STAGEA(A0, A1) do { *(uint4*)wr0 = A0; *(uint4*)wr1 = A1; } while (0)
#define STAGEB(BR) do { \
    _Pragma("unroll") \
    for (int rr = 0; rr < 4; ++rr) { \
        bf16x8 p; \
        _Pragma("unroll") \
        for (int j = 0; j < 8; ++j) p[j] = (bf16)BR[j][rr]; \
        *(bf16x8*)(bwr + rr * 8) = p; \
    } } while (0)
#define COMPUTE() do { \
    _Pragma("unroll") \
    for (int kc = 0; kc < 2; ++kc) { \
        bf16x8 afr[4]; \
        _Pragma("unroll") \
        for (int mf = 0; mf < 4; ++mf) \
            afr[mf] = *(const bf16x8*)(As + ((size_t)((mf * 2 + kc) * 64 + lane)) * 8); \
        const int Rg = wave * 2 + kc, Ru = (wave + 4) * 2 + kc; \
        bf16x8 bg = *(const bf16x8*)(Bs + ((size_t)(Rg * 64 + (Rg >> 1) + lane)) * 8); \
        bf16x8 bu = *(const bf16x8*)(Bs + ((size_t)(Ru * 64 + (Ru >> 1) + lane)) * 8); \
        _Pragma("unroll") \
        for (int mf = 0; mf < 4; ++mf) { \
            accg[mf] = __builtin_amdgcn_mfma_f32_16x16x32_bf16(afr[mf], bg, accg[mf], 0, 0, 0); \
            accu[mf] = __builtin_amdgcn_mfma_f32_16x16x32_bf16(afr[mf], bu, accu[mf], 0, 0, 0); \
        } \
    } } while (0)

    LOADA(a0a, a0b, 0);
    LOADB(br0, 0);
    #pragma unroll 1
    for (int kb = 0; kb < 16; kb += 2) {
        BARRIER();
        STAGEA(a0a, a0b);  STAGEB(br0);
        LOADA(a1a, a1b, kb + 1);  LOADB(br1, kb + 1);
        BARRIER();
        COMPUTE();

        BARRIER();
        STAGEA(a1a, a1b);  STAGEB(br1);
        LOADA(a0a, a0b, kb + 2);  LOADB(br0, kb + 2);
        BARRIER();
        COMPUTE();
    }
#undef LOADA
#undef LOADB
#undef STAGEA
#undef STAGEB
#undef COMPUTE

    // --- epilogue ---
    const int nb_g = bx * 4 + wave;
    const int cg = nb_g * 16 + r;
    const float bgv = b13[e * 2 * IDIM + cg];
    const float buv = b13[e * 2 * IDIM + IDIM + cg];
    #pragma unroll
    for (int mf = 0; mf < 4; ++mf) {
        #pragma unroll
        for (int rg = 0; rg < 4; ++rg) {
            const int row = mf * 16 + q * 4 + rg;
            if (m0 + row < ne) {
                const float hg = accg[mf][rg] + bgv;
                const float hu = accu[mf][rg] + buv;
                const float gt = fminf(hg, LIMIT);
                const float up = fminf(fmaxf(hu, -LIMIT), LIMIT);
                const float av = (up + 1.0f) * gt / (1.0f + expf(-ALPHA * gt));
                act[(size_t)(sb + m0 + row) * IDIM + cg] = (bf16)av;
            }
        }
    }
}

// ---------------------------------------------------------------------------
// Kernel 3: grouped down GEMM + weighted atomic combine. Same direct-fp32
// B staging (128 cols/block). grid: (8, 80); wave w: nb = bx*8 + w*2 + {0,1}.
// ---------------------------------------------------------------------------
__global__ __launch_bounds__(256) void k_down7(
    const bf16* __restrict__ act, const float* __restrict__ w2,
    const float* __restrict__ b2, const int* __restrict__ cnt,
    const int* __restrict__ tok_list, const float* __restrict__ wgt_list,
    float* __restrict__ out)
{
    const int ti = blockIdx.y, bx = blockIdx.x;
    const int tid = threadIdx.x, lane = tid & 63, wave = tid >> 6;
    const int q = lane >> 4, r = lane & 15;

    __shared__ __align__(16) bf16 As[8 * 64 * 8];
    __shared__ __align__(16) bf16 Bs[1032 * 8];
    __shared__ int sm[5];

    inline_scan(cnt, ti, tid, sm);
    if (ti >= sm[0]) return;
    const int e = sm[1], m0 = sm[2], ne = sm[3], sb = sm[4];

    const int m   = tid >> 2, kq = tid & 3;
    const int mf_s = m >> 4, r_s = m & 15;
    const int kc_s = kq >> 1, q_s = (kq & 1) * 2;
    bf16* wr0 = As + ((size_t)((mf_s * 2 + kc_s) * 64 + q_s * 16 + r_s)) * 8;
    bf16* wr1 = wr0 + 16 * 8;
    int srow = m0 + m; srow = srow < ne ? srow : ne - 1;
    const bf16* pA = act + (size_t)(sb + srow) * IDIM + kq * 16;

    const int c4 = tid & 31, q6 = tid >> 5;
    const int kcs = q6 >> 2, qs = q6 & 3;
    const int cc = c4 * 4;
    const int fB = c4 >> 2, r0 = (c4 & 3) * 4;
    const int RB = fB * 2 + kcs;
    bf16* bwr = Bs + ((size_t)(RB * 64 + (RB >> 1) + qs * 16 + r0)) * 8;
    const float* pB = w2 + (size_t)e * IDIM * H_
                         + (size_t)(kcs * 32 + qs * 8) * H_ + bx * 128 + cc;

    f32x4 acc[4][2] = {};
    uint4  a0a, a0b, a1a, a1b;
    f32x4  br0[8], br1[8];

#define LOADA(A0, A1, s) do { const int ss_ = (s) < 16 ? (s) : 15; \
    A0 = *(const uint4*)(pA + ss_ * 64); \
    A1 = *(const uint4*)(pA + ss_ * 64 + 8); } while (0)
#define LOADB(BR, s) do { const int ss_ = (s) < 16 ? (s) : 15; \
    _Pragma("unroll") \
    for (int j = 0; j < 8; ++j) \
        BR[j] = *(const f32x4*)(pB + (size_t)(ss_ * 64 + j) * H_); } while (0)
#define STAGEA(A0, A1) do { *(uint4*)wr0 = A0; *(uint4*)wr1 = A1; } while (0)
#define STAGEB(BR) do { \
    _Pragma("unroll") \
    for (int rr = 0; rr < 4; ++rr) { \
        bf16x8 p; \
        _Pragma("unroll") \
        for (int j = 0; j < 8; ++j) p[j] = (bf16)BR[j][rr]; \
        *(bf16x8*)(bwr + rr * 8) = p; \
    } } while (0)
#define COMPUTE() do { \
    _Pragma("unroll") \
    for (int kc = 0; kc < 2; ++kc) { \
        bf16x8 afr[4]; \
        _Pragma("unroll") \
        for (int mf = 0; mf < 4; ++mf) \
            afr[mf] = *(const bf16x8*)(As + ((size_t)((mf * 2 + kc) * 64 + lane)) * 8); \
        const int R0 = (wave * 2) * 2 + kc, R1 = (wave * 2 + 1) * 2 + kc; \
        bf16x8 b0 = *(const bf16x8*)(Bs + ((size_t)(R0 * 64 + (R0 >> 1) + lane)) * 8); \
        bf16x8 b1 = *(const bf16x8*)(Bs + ((size_t)(R1 * 64 + (R1 >> 1) + lane)) * 8); \
        _Pragma("unroll") \
        for (int mf = 0; mf < 4; ++mf) { \
            acc[mf][0] = __builtin_amdgcn_mfma_f32_16x16x32_bf16(afr[mf], b0, acc[mf][0], 0, 0, 0); \
            acc[mf][1] = __builtin_amdgcn_mfma_f32_16x16x32_bf16(afr[mf], b1, acc[mf][1], 0, 0, 0); \
        } \
    } } while (0)

    LOADA(a0a, a0b, 0);
    LOADB(br0, 0);
    #pragma unroll 1
    for (int kb = 0; kb < 16; kb += 2) {
        BARRIER();
        STAGEA(a0a, a0b);  STAGEB(br0);
        LOADA(a1a, a1b, kb + 1);  LOADB(br1, kb + 1);
        BARRIER();
        COMPUTE();

        BARRIER();
        STAGEA(a1a, a1b);  STAGEB(br1);
        LOADA(a0a, a0b, kb + 2);  LOADB(br0, kb + 2);
        BARRIER();
        COMPUTE();
    }
#undef LOADA
#undef LOADB
#undef STAGEA
#undef STAGEB
#undef COMPUTE

    const int nb0 = bx * 8 + wave * 2;
    #pragma unroll
    for (int nf = 0; nf < 2; ++nf) {
        const int ch = (nb0 + nf) * 16 + r;
        const float bb = b2[e * H_ + ch];
        #pragma unroll
        for (int mf = 0; mf < 4; ++mf) {
            #pragma unroll
            for (int rg = 0; rg < 4; ++rg) {
                const int row = mf * 16 + q * 4 + rg;
                const int s = m0 + row;
                if (s < ne) {
                    const int   tok = tok_list[e * T_ + s];
                    const float w   = wgt_list[e * T_ + s];
                    atomicAdd(&out[(size_t)tok * H_ + ch], w * (acc[mf][nf][rg] + bb));
                }
            }
        }
    }
}

// ---------------------------------------------------------------------------
extern "C" void kernel_launch(void* const* d_in, const int* in_sizes, int n_in,
                              void* d_out, int out_size, void* d_ws, size_t ws_size,
                              hipStream_t stream)
{
    const float* x        = (const float*)d_in[0];
    const float* norm_w   = (const float*)d_in[1];
    const float* router_w = (const float*)d_in[2];
    const float* router_b = (const float*)d_in[3];
    const float* w13      = (const float*)d_in[4];
    const float* b13      = (const float*)d_in[5];
    const float* w2       = (const float*)d_in[6];
    const float* b2       = (const float*)d_in[7];
    const float* manual_w = (const float*)d_in[8];
    const int*   layer_i  = (const int*)d_in[9];
    float* out = (float*)d_out;

    char* ws = (char*)d_ws;
    bf16*  tB   = (bf16*)ws;                              // 2 MB @ 0
    bf16*  act  = (bf16*)(ws + (2ull << 20));             // 8 MB @ 2M
    char*  meta = ws + (10ull << 20);
    int*   cnt      = (int*)meta;                         // 16 ints
    int*   tok_list = (int*)(meta + (16ull << 10));       // 64 KB
    float* wgt_list = (float*)(meta + (16ull << 10) + (64ull << 10)); // 64 KB

    hipMemsetAsync(cnt, 0, E_ * sizeof(int), stream);

    k_rms_router<<<T_, 256, 0, stream>>>(x, norm_w, router_w, router_b,
                                         manual_w, layer_i, tB, out,
                                         cnt, tok_list, wgt_list);

    dim3 gg(16, 80);
    k_gateup7<<<gg, 256, 0, stream>>>(tB, w13, b13, cnt, tok_list, act);
    dim3 gd(8, 80);
    k_down7<<<gd, 256, 0, stream>>>(act, w2, b2, cnt, tok_list, wgt_list, out);
}

// Round 8
// 371.145 us; speedup vs baseline: 1.2912x; 1.0056x over previous
//
#include <hip/hip_runtime.h>

#define T_    1024
#define H_    1024
#define IDIM  1024
#define E_    16
#define TOPK  4
#define ALPHA 1.702f
#define LIMIT 7.0f

typedef __bf16 bf16;
typedef __bf16 bf16x4 __attribute__((ext_vector_type(4)));
typedef __bf16 bf16x8 __attribute__((ext_vector_type(8)));
typedef float  f32x4  __attribute__((ext_vector_type(4)));

// Raw barrier WITHOUT vmcnt(0) drain: LDS ordering only (proven).
#define BARRIER() do { \
    asm volatile("s_waitcnt lgkmcnt(0)" ::: "memory"); \
    __builtin_amdgcn_s_barrier(); } while (0)

// ---------------------------------------------------------------------------
// Kernel 1: RMSNorm + router logits + softmax/top-4 + routing lists.
// ---------------------------------------------------------------------------
__global__ __launch_bounds__(256) void k_rms_router(
    const float* __restrict__ x, const float* __restrict__ nw,
    const float* __restrict__ rw, const float* __restrict__ rb,
    const float* __restrict__ mw, const int* __restrict__ lidx,
    bf16* __restrict__ tB, float* __restrict__ out,
    int* __restrict__ cnt, int* __restrict__ tok_list,
    float* __restrict__ wgt_list)
{
    const int t = blockIdx.x, tid = threadIdx.x;
    const int lane = tid & 63, wave = tid >> 6;
    __shared__ float tbuf[H_];
    __shared__ float red[4];
    __shared__ float logits[E_];

    float4 xv = ((const float4*)(x + (size_t)t * H_))[tid];
    float4 wv = ((const float4*)nw)[tid];
    float ssq = xv.x*xv.x + xv.y*xv.y + xv.z*xv.z + xv.w*xv.w;
    #pragma unroll
    for (int off = 32; off; off >>= 1) ssq += __shfl_xor(ssq, off);
    if (lane == 0) red[wave] = ssq;
    __syncthreads();
    const float rms = rsqrtf((red[0] + red[1] + red[2] + red[3]) * (1.0f / H_) + 1e-5f);

    float4 tv;
    tv.x = xv.x * rms * wv.x;
    tv.y = xv.y * rms * wv.y;
    tv.z = xv.z * rms * wv.z;
    tv.w = xv.w * rms * wv.w;

    ((float4*)(out + (size_t)t * H_))[tid] = xv;      // residual init
    ((float4*)tbuf)[tid] = tv;
    bf16x4 tb = { (bf16)tv.x, (bf16)tv.y, (bf16)tv.z, (bf16)tv.w };
    *(bf16x4*)(tB + (size_t)t * H_ + tid * 4) = tb;
    __syncthreads();

    #pragma unroll
    for (int ei = 0; ei < 4; ++ei) {
        const int e = wave * 4 + ei;
        const float* wr = rw + (size_t)e * H_;
        float s = 0.f;
        #pragma unroll
        for (int j = 0; j < 16; ++j) {
            const int c = lane + j * 64;
            s += tbuf[c] * wr[c];
        }
        #pragma unroll
        for (int off = 32; off; off >>= 1) s += __shfl_xor(s, off);
        if (lane == 0) logits[e] = s + rb[e];
    }
    __syncthreads();

    if (tid == 0) {
        float g[E_];
        #pragma unroll
        for (int e = 0; e < E_; ++e) g[e] = logits[e];

        const int li = lidx[0];
        float ma = 0.f, lw[E_];
        #pragma unroll
        for (int e = 0; e < E_; ++e) { lw[e] = mw[li * E_ + e]; ma = fmaxf(ma, fabsf(lw[e])); }
        if (ma > 0.f) {
            float mx = -1e30f;
            for (int e = 0; e < E_; ++e) mx = fmaxf(mx, g[e]);
            float se = 0.f;
            for (int e = 0; e < E_; ++e) se += expf(g[e] - mx);
            const float lse = logf(se) + mx;
            float gl[E_], gmx = -1e30f, gmn = 1e30f;
            for (int e = 0; e < E_; ++e) { gl[e] = g[e] - lse; gmx = fmaxf(gmx, gl[e]); gmn = fminf(gmn, gl[e]); }
            for (int e = 0; e < E_; ++e) {
                if (lw[e] > 0.f)      gl[e] = gmx + 0.01f;
                else if (lw[e] < 0.f) gl[e] = gmn - 0.01f;
                g[e] = gl[e];
            }
        }

        float mx = -1e30f;
        #pragma unroll
        for (int e = 0; e < E_; ++e) mx = fmaxf(mx, g[e]);
        float p[E_];
        #pragma unroll
        for (int e = 0; e < E_; ++e) p[e] = expf(g[e] - mx);

        bool used[E_] = {};
        int   idx[TOPK];
        float twv[TOPK];
        float ssum = 0.f;
        for (int k = 0; k < TOPK; ++k) {
            int best = -1; float bv = -1e30f;
            for (int e = 0; e < E_; ++e)
                if (!used[e] && p[e] > bv) { bv = p[e]; best = e; }
            used[best] = true; idx[k] = best; twv[k] = bv; ssum += bv;
        }
        const float inv = 1.f / ssum;
        for (int k = 0; k < TOPK; ++k) {
            const int e = idx[k];
            const int slot = atomicAdd(&cnt[e], 1);
            tok_list[e * T_ + slot] = t;
            wgt_list[e * T_ + slot] = twv[k] * inv;
        }
    }
}

// ---------------------------------------------------------------------------
// Inline routing scan (single-thread, 128-row tiles). {tiln, e, m0, ne, sb}.
// ---------------------------------------------------------------------------
__device__ __forceinline__ void inline_scan(const int* __restrict__ cnt,
                                            int ti, int tid, int* sm)
{
    if (tid == 0) {
        int c0[E_];
        #pragma unroll
        for (int e = 0; e < E_; ++e) c0[e] = cnt[e];
        int s = 0, nt = 0, ee = 0, mm0 = 0, nee = 0, sbb = 0;
        #pragma unroll
        for (int e = 0; e < E_; ++e) {
            const int c = c0[e];
            const int tcnt = (c + 127) >> 7;
            if (ti >= nt && ti < nt + tcnt) {
                ee = e; mm0 = (ti - nt) * 128; nee = c; sbb = s;
            }
            s += c; nt += tcnt;
        }
        sm[0] = nt; sm[1] = ee; sm[2] = mm0; sm[3] = nee; sm[4] = sbb;
    }
    __syncthreads();
}

// ---------------------------------------------------------------------------
// Kernel 2: grouped gate_up GEMM, BM=128 / 8 waves (512 thr). fp32 weights
// consumed directly (no repack). Wave (wm=w>>2, wn=w&3): rows wm*64..+63,
// gate nb = bx*4+wn, up nb = gate+64. Per-wave acc = 32 VGPR (unchanged
// from proven kernel). B re-read per column HALVED vs BM=64.
// grid: (16, 48).
// ---------------------------------------------------------------------------
__global__ __launch_bounds__(512) void k_gateup8(
    const bf16* __restrict__ tB, const float* __restrict__ w13,
    const float* __restrict__ b13, const int* __restrict__ cnt,
    const int* __restrict__ tok_list, bf16* __restrict__ act)
{
    const int ti = blockIdx.y, bx = blockIdx.x;
    const int tid = threadIdx.x, lane = tid & 63, wave = tid >> 6;
    const int wm = wave >> 2, wn = wave & 3;
    const int q = lane >> 4, r = lane & 15;

    __shared__ __align__(16) bf16 As[16 * 64 * 8];         // 16 KB
    __shared__ __align__(16) bf16 Bs[1032 * 8];            // 16.5 KB (skewed)
    __shared__ int sm[5];

    inline_scan(cnt, ti, tid, sm);
    if (ti >= sm[0]) return;
    const int e = sm[1], m0 = sm[2], ne = sm[3], sb = sm[4];

    // --- A staging: thread -> row m = tid>>2 (0..127), 32B chunk kq = tid&3 ---
    const int m   = tid >> 2, kq = tid & 3;
    const int mf_s = m >> 4, r_s = m & 15;
    const int kc_s = kq >> 1, q_s = (kq & 1) * 2;
    bf16* wr0 = As + ((size_t)((mf_s * 2 + kc_s) * 64 + q_s * 16 + r_s)) * 8;
    bf16* wr1 = wr0 + 16 * 8;
    int srow = m0 + m; srow = srow < ne ? srow : ne - 1;
    const bf16* pA = tB + (size_t)tok_list[e * T_ + srow] * H_ + kq * 16;

    // --- B staging: c4 = tid&31 (col quad), q6 = tid>>5 (k sub-block) ---
    const int c4 = tid & 31, q6 = tid >> 5;
    const int kcs = q6 >> 3, qs = (q6 >> 1) & 3, jh = q6 & 1;
    const int cc = c4 * 4;                       // 0..124 (gate | up halves)
    const int fB = c4 >> 2, r0 = (c4 & 3) * 4;
    const int RB = fB * 2 + kcs;
    bf16* bwr = Bs + ((size_t)(RB * 64 + (RB >> 1) + qs * 16 + r0)) * 8 + jh * 4;
    const int col = (cc < 64) ? (bx * 64 + cc) : (IDIM + bx * 64 + (cc - 64));
    const float* pB = w13 + (size_t)e * H_ * (2 * IDIM)
                          + (size_t)(kcs * 32 + qs * 8 + jh * 4) * (2 * IDIM) + col;

    f32x4 accg[4] = {};
    f32x4 accu[4] = {};
    uint4  a0a, a0b, a1a, a1b;
    f32x4  br0[4], br1[4];

#define LOADA(A0, A1, s) do { const int ss_ = (s) < 16 ? (s) : 15; \
    A0 = *(const uint4*)(pA + ss_ * 64); \
    A1 = *(const uint4*)(pA + ss_ * 64 + 8); } while (0)
#define LOADB(BR, s) do { const int ss_ = (s) < 16 ? (s) : 15; \
    _Pragma("unroll") \
    for (int j2 = 0; j2 < 4; ++j2) \
        BR[j2] = *(const f32x4*)(pB + (size_t)(ss_ * 64 + j2) * (2 * IDIM)); } while (0)
#define STAGEA(A0, A1) do { *(uint4*)wr0 = A0; *(uint4*)wr1 = A1; } while (0)
#define STAGEB(BR) do { \
    _Pragma("unroll") \
    for (int rr = 0; rr < 4; ++rr) { \
        bf16x4 p = { (bf16)BR[0][rr], (bf16)BR[1][rr], \
                     (bf16)BR[2][rr], (bf16)BR[3][rr] }; \
        *(bf16x4*)(bwr + rr * 8) = p; \
    } } while (0)
#define COMPUTE() do { \
    _Pragma("unroll") \
    for (int kc = 0; kc < 2; ++kc) { \
        bf16x8 afr[4]; \
        _Pragma("unroll") \
        for (int mf = 0; mf < 4; ++mf) \
            afr[mf] = *(const bf16x8*)(As + ((size_t)(((wm * 4 + mf) * 2 + kc) * 64 + lane)) * 8); \
        const int Rg = wn * 2 + kc, Ru = (wn + 4) * 2 + kc; \
        bf16x8 bg = *(const bf16x8*)(Bs + ((size_t)(Rg * 64 + (Rg >> 1) + lane)) * 8); \
        bf16x8 bu = *(const bf16x8*)(Bs + ((size_t)(Ru * 64 + (Ru >> 1) + lane)) * 8); \
        _Pragma("unroll") \
        for (int mf = 0; mf < 4; ++mf) { \
            accg[mf] = __builtin_amdgcn_mfma_f32_16x16x32_bf16(afr[mf], bg, accg[mf], 0, 0, 0); \
            accu[mf] = __builtin_amdgcn_mfma_f32_16x16x32_bf16(afr[mf], bu, accu[mf], 0, 0, 0); \
        } \
    } } while (0)

    LOADA(a0a, a0b, 0);
    LOADB(br0, 0);
    #pragma unroll 1
    for (int kb = 0; kb < 16; kb += 2) {
        BARRIER();
        STAGEA(a0a, a0b);  STAGEB(br0);
        LOADA(a1a, a1b, kb + 1);  LOADB(br1, kb + 1);
        BARRIER();
        COMPUTE();

        BARRIER();
        STAGEA(a1a, a1b);  STAGEB(br1);
        LOADA(a0a, a0b, kb + 2);  LOADB(br0, kb + 2);
        BARRIER();
        COMPUTE();
    }
#undef LOADA
#undef LOADB
#undef STAGEA
#undef STAGEB
#undef COMPUTE

    // --- epilogue ---
    const int nb_g = bx * 4 + wn;
    const int cg = nb_g * 16 + r;
    const float bgv = b13[e * 2 * IDIM + cg];
    const float buv = b13[e * 2 * IDIM + IDIM + cg];
    #pragma unroll
    for (int mf = 0; mf < 4; ++mf) {
        #pragma unroll
        for (int rg = 0; rg < 4; ++rg) {
            const int row = wm * 64 + mf * 16 + q * 4 + rg;
            if (m0 + row < ne) {
                const float hg = accg[mf][rg] + bgv;
                const float hu = accu[mf][rg] + buv;
                const float gt = fminf(hg, LIMIT);
                const float up = fminf(fmaxf(hu, -LIMIT), LIMIT);
                const float av = (up + 1.0f) * gt / (1.0f + expf(-ALPHA * gt));
                act[(size_t)(sb + m0 + row) * IDIM + cg] = (bf16)av;
            }
        }
    }
}

// ---------------------------------------------------------------------------
// Kernel 3: grouped down GEMM + weighted atomic combine, BM=128 / 8 waves.
// Wave (wm=w>>2, wn=w&3): rows wm*64..+63, nb = bx*8 + wn*2 + {0,1}.
// grid: (8, 48).
// ---------------------------------------------------------------------------
__global__ __launch_bounds__(512) void k_down8(
    const bf16* __restrict__ act, const float* __restrict__ w2,
    const float* __restrict__ b2, const int* __restrict__ cnt,
    const int* __restrict__ tok_list, const float* __restrict__ wgt_list,
    float* __restrict__ out)
{
    const int ti = blockIdx.y, bx = blockIdx.x;
    const int tid = threadIdx.x, lane = tid & 63, wave = tid >> 6;
    const int wm = wave >> 2, wn = wave & 3;
    const int q = lane >> 4, r = lane & 15;

    __shared__ __align__(16) bf16 As[16 * 64 * 8];
    __shared__ __align__(16) bf16 Bs[1032 * 8];
    __shared__ int sm[5];

    inline_scan(cnt, ti, tid, sm);
    if (ti >= sm[0]) return;
    const int e = sm[1], m0 = sm[2], ne = sm[3], sb = sm[4];

    const int m   = tid >> 2, kq = tid & 3;
    const int mf_s = m >> 4, r_s = m & 15;
    const int kc_s = kq >> 1, q_s = (kq & 1) * 2;
    bf16* wr0 = As + ((size_t)((mf_s * 2 + kc_s) * 64 + q_s * 16 + r_s)) * 8;
    bf16* wr1 = wr0 + 16 * 8;
    int srow = m0 + m; srow = srow < ne ? srow : ne - 1;
    const bf16* pA = act + (size_t)(sb + srow) * IDIM + kq * 16;

    const int c4 = tid & 31, q6 = tid >> 5;
    const int kcs = q6 >> 3, qs = (q6 >> 1) & 3, jh = q6 & 1;
    const int cc = c4 * 4;
    const int fB = c4 >> 2, r0 = (c4 & 3) * 4;
    const int RB = fB * 2 + kcs;
    bf16* bwr = Bs + ((size_t)(RB * 64 + (RB >> 1) + qs * 16 + r0)) * 8 + jh * 4;
    const float* pB = w2 + (size_t)e * IDIM * H_
                         + (size_t)(kcs * 32 + qs * 8 + jh * 4) * H_ + bx * 128 + cc;

    f32x4 acc[4][2] = {};
    uint4  a0a, a0b, a1a, a1b;
    f32x4  br0[4], br1[4];

#define LOADA(A0, A1, s) do { const int ss_ = (s) < 16 ? (s) : 15; \
    A0 = *(const uint4*)(pA + ss_ * 64); \
    A1 = *(const uint4*)(pA + ss_ * 64 + 8); } while (0)
#define LOADB(BR, s) do { const int ss_ = (s) < 16 ? (s) : 15; \
    _Pragma("unroll") \
    for (int j2 = 0; j2 < 4; ++j2) \
        BR[j2] = *(const f32x4*)(pB + (size_t)(ss_ * 64 + j2) * H_); } while (0)
#define STAGEA(A0, A1) do { *(uint4*)wr0 = A0; *(uint4*)wr1 = A1; } while (0)
#define STAGEB(BR) do { \
    _Pragma("unroll") \
    for (int rr = 0; rr < 4; ++rr) { \
        bf16x4 p = { (bf16)BR[0][rr], (bf16)BR[1][rr], \
                     (bf16)BR[2][rr], (bf16)BR[3][rr] }; \
        *(bf16x4*)(bwr + rr * 8) = p; \
    } } while (0)
#define COMPUTE() do { \
    _Pragma("unroll") \
    for (int kc = 0; kc < 2; ++kc) { \
        bf16x8 afr[4]; \
        _Pragma("unroll") \
        for (int mf = 0; mf < 4; ++mf) \
            afr[mf] = *(const bf16x8*)(As + ((size_t)(((wm * 4 + mf) * 2 + kc) * 64 + lane)) * 8); \
        const int R0 = (wn * 2) * 2 + kc, R1 = (wn * 2 + 1) * 2 + kc; \
        bf16x8 b0 = *(const bf16x8*)(Bs + ((size_t)(R0 * 64 + (R0 >> 1) + lane)) * 8); \
        bf16x8 b1 = *(const bf16x8*)(Bs + ((size_t)(R1 * 64 + (R1 >> 1) + lane)) * 8); \
        _Pragma("unroll") \
        for (int mf = 0; mf < 4; ++mf) { \
            acc[mf][0] = __builtin_amdgcn_mfma_f32_16x16x32_bf16(afr[mf], b0, acc[mf][0], 0, 0, 0); \
            acc[mf][1] = __builtin_amdgcn_mfma_f32_16x16x32_bf16(afr[mf], b1, acc[mf][1], 0, 0, 0); \
        } \
    } } while (0)

    LOADA(a0a, a0b, 0);
    LOADB(br0, 0);
    #pragma unroll 1
    for (int kb = 0; kb < 16; kb += 2) {
        BARRIER();
        STAGEA(a0a, a0b);  STAGEB(br0);
        LOADA(a1a, a1b, kb + 1);  LOADB(br1, kb + 1);
        BARRIER();
        COMPUTE();

        BARRIER();
        STAGEA(a1a, a1b);  STAGEB(br1);
        LOADA(a0a, a0b, kb + 2);  LOADB(br0, kb + 2);
        BARRIER();
        COMPUTE();
    }
#undef LOADA
#undef LOADB
#undef STAGEA
#undef STAGEB
#undef COMPUTE

    const int nb0 = bx * 8 + wn * 2;
    #pragma unroll
    for (int nf = 0; nf < 2; ++nf) {
        const int ch = (nb0 + nf) * 16 + r;
        const float bb = b2[e * H_ + ch];
        #pragma unroll
        for (int mf = 0; mf < 4; ++mf) {
            #pragma unroll
            for (int rg = 0; rg < 4; ++rg) {
                const int row = wm * 64 + mf * 16 + q * 4 + rg;
                const int s = m0 + row;
                if (s < ne) {
                    const int   tok = tok_list[e * T_ + s];
                    const float w   = wgt_list[e * T_ + s];
                    atomicAdd(&out[(size_t)tok * H_ + ch], w * (acc[mf][nf][rg] + bb));
                }
            }
        }
    }
}

// ---------------------------------------------------------------------------
extern "C" void kernel_launch(void* const* d_in, const int* in_sizes, int n_in,
                              void* d_out, int out_size, void* d_ws, size_t ws_size,
                              hipStream_t stream)
{
    const float* x        = (const float*)d_in[0];
    const float* norm_w   = (const float*)d_in[1];
    const float* router_w = (const float*)d_in[2];
    const float* router_b = (const float*)d_in[3];
    const float* w13      = (const float*)d_in[4];
    const float* b13      = (const float*)d_in[5];
    const float* w2       = (const float*)d_in[6];
    const float* b2       = (const float*)d_in[7];
    const float* manual_w = (const float*)d_in[8];
    const int*   layer_i  = (const int*)d_in[9];
    float* out = (float*)d_out;

    char* ws = (char*)d_ws;
    bf16*  tB   = (bf16*)ws;                              // 2 MB @ 0
    bf16*  act  = (bf16*)(ws + (2ull << 20));             // 8 MB @ 2M
    char*  meta = ws + (10ull << 20);
    int*   cnt      = (int*)meta;                         // 16 ints
    int*   tok_list = (int*)(meta + (16ull << 10));       // 64 KB
    float* wgt_list = (float*)(meta + (16ull << 10) + (64ull << 10)); // 64 KB

    hipMemsetAsync(cnt, 0, E_ * sizeof(int), stream);

    k_rms_router<<<T_, 256, 0, stream>>>(x, norm_w, router_w, router_b,
                                         manual_w, layer_i, tB, out,
                                         cnt, tok_list, wgt_list);

    dim3 gg(16, 48);
    k_gateup8<<<gg, 512, 0, stream>>>(tB, w13, b13, cnt, tok_list, act);
    dim3 gd(8, 48);
    k_down8<<<gd, 512, 0, stream>>>(act, w2, b2, cnt, tok_list, wgt_list, out);
}